// Round 1
// baseline (256.147 us; speedup 1.0000x reference)
//
#include <hip/hip_runtime.h>

typedef unsigned short u16;
typedef short bf16x8 __attribute__((ext_vector_type(8)));
typedef float f32x4 __attribute__((ext_vector_type(4)));

#define MFMA(a, b, c) __builtin_amdgcn_mfma_f32_16x16x32_bf16(a, b, c, 0, 0, 0)

// f32 -> bf16 round-to-nearest-even
__device__ __forceinline__ u16 f2bf(float f) {
  unsigned int u = __float_as_uint(f);
  u = (u + 0x7FFFu + ((u >> 16) & 1u)) >> 16;
  return (u16)u;
}

// async global->LDS, 16B per lane; lds dest must be wave-uniform base (HW adds lane*16)
#define GLOAD16(gp, lp)                                                        \
  __builtin_amdgcn_global_load_lds(                                            \
      (const __attribute__((address_space(1))) void*)(gp),                     \
      (__attribute__((address_space(3))) void*)(lp), 16, 0, 0)

// ---------------- prep kernels ----------------

__global__ void rope_tables(float* __restrict__ cost, float* __restrict__ sint) {
  int idx = blockIdx.x * 256 + threadIdx.x;
  if (idx >= 2048 * 32) return;
  int t = idx >> 5, i = idx & 31;
  // inv_freq = 10000^(-i/32) = exp(-i * ln(10000)/32)
  float invf = expf(-(float)i * 0.28782313662425572f);
  float ang = (float)t * invf;
  cost[idx] = cosf(ang);
  sint[idx] = sinf(ang);
}

__global__ void cast_x(const float* __restrict__ x, u16* __restrict__ xb, int n) {
  int i = (blockIdx.x * 256 + threadIdx.x) * 4;
  if (i >= n) return;
  float4 v = *(const float4*)(x + i);
  u16 o0 = f2bf(v.x), o1 = f2bf(v.y), o2 = f2bf(v.z), o3 = f2bf(v.w);
  ushort4 o = make_ushort4(o0, o1, o2, o3);
  *(ushort4*)(xb + i) = o;
}

// Wqkv_t[qkv*768 + h*64 + d][c] = W_{qkv}[h][c][d]   (bf16, B^T layout for GEMM)
__global__ void prep_wqkv(const float* __restrict__ WQ, const float* __restrict__ WK,
                          const float* __restrict__ WV, u16* __restrict__ Wt) {
  __shared__ float tile[32][33];
  const int z = blockIdx.z;              // 0..35
  const int qkv = z / 12, h = z - qkv * 12;
  const float* W = (qkv == 0 ? WQ : qkv == 1 ? WK : WV) + (size_t)h * 768 * 64;
  const int k0 = blockIdx.x * 32, d0 = blockIdx.y * 32;
  const int tx = threadIdx.x, ty = threadIdx.y;
#pragma unroll
  for (int it = 0; it < 4; it++)
    tile[ty + it * 8][tx] = W[(size_t)(k0 + ty + it * 8) * 64 + d0 + tx];
  __syncthreads();
  u16* out = Wt + (size_t)(qkv * 768 + h * 64 + d0) * 768 + k0;
#pragma unroll
  for (int it = 0; it < 4; it++)
    out[(size_t)(ty + it * 8) * 768 + tx] = f2bf(tile[tx][ty + it * 8]);
}

// WoT[m][hd] = W_O[hd][m]  (768x768 transpose, bf16)
__global__ void prep_wo(const float* __restrict__ WO, u16* __restrict__ Wt) {
  __shared__ float tile[32][33];
  const int a0 = blockIdx.x * 32, m0 = blockIdx.y * 32;
  const int tx = threadIdx.x, ty = threadIdx.y;
#pragma unroll
  for (int it = 0; it < 4; it++)
    tile[ty + it * 8][tx] = WO[(size_t)(a0 + ty + it * 8) * 768 + m0 + tx];
  __syncthreads();
#pragma unroll
  for (int it = 0; it < 4; it++)
    Wt[(size_t)(m0 + ty + it * 8) * 768 + a0 + tx] = f2bf(tile[tx][ty + it * 8]);
}

// ---------------- GEMM (128x128 tile, BK=32, 4 waves, 16x16x32 bf16 MFMA) ----------------
// A [M][LDA] bf16 row-major, Bt [N][LDB] bf16 (B transposed: Bt[n][k]).
// MODE 0: QKV epilogue (bias + RoPE + 1/8 into Q, V scattered to Vt[bh][d][t])
// MODE 1: out proj epilogue (+= bO, fp32 store)
template <int MODE>
__global__ __launch_bounds__(256) void gemm_bt(
    const u16* __restrict__ A, const u16* __restrict__ Bt, int K, int LDA, int LDB,
    const float* __restrict__ bQ, const float* __restrict__ bK, const float* __restrict__ bV,
    const float* __restrict__ cost, const float* __restrict__ sint,
    u16* __restrict__ Qb, u16* __restrict__ Kb, u16* __restrict__ Vt,
    const float* __restrict__ bO, float* __restrict__ Out) {
  __shared__ u16 As[128 * 32];
  __shared__ u16 Bs[128 * 32];
  const int tid = threadIdx.x;
  const int w = tid >> 6, l = tid & 63;
  const int lr = l >> 4, lc = l & 15;
  const int wr = w >> 1, wc = w & 1;
  const int m0 = blockIdx.x * 128, n0 = blockIdx.y * 128;

  f32x4 acc[4][4];
#pragma unroll
  for (int mi = 0; mi < 4; mi++)
#pragma unroll
    for (int ni = 0; ni < 4; ni++) acc[mi][ni] = (f32x4){0.f, 0.f, 0.f, 0.f};

  for (int kt = 0; kt < K; kt += 32) {
    // stage: rows (issue*64 + w*16 + l/4), cols (l%4)*8, 16B per lane
    const u16* ga = A + (size_t)(m0 + w * 16 + (l >> 2)) * LDA + kt + (l & 3) * 8;
    const u16* gb = Bt + (size_t)(n0 + w * 16 + (l >> 2)) * LDB + kt + (l & 3) * 8;
    GLOAD16(ga, &As[w * 512]);
    GLOAD16(ga + (size_t)64 * LDA, &As[2048 + w * 512]);
    GLOAD16(gb, &Bs[w * 512]);
    GLOAD16(gb + (size_t)64 * LDB, &Bs[2048 + w * 512]);
    __syncthreads();

    bf16x8 af[4], bfr[4];
#pragma unroll
    for (int mi = 0; mi < 4; mi++)
      af[mi] = *(const bf16x8*)&As[(wr * 64 + mi * 16 + lc) * 32 + lr * 8];
#pragma unroll
    for (int ni = 0; ni < 4; ni++)
      bfr[ni] = *(const bf16x8*)&Bs[(wc * 64 + ni * 16 + lc) * 32 + lr * 8];
#pragma unroll
    for (int mi = 0; mi < 4; mi++)
#pragma unroll
      for (int ni = 0; ni < 4; ni++)
        acc[mi][ni] = MFMA(af[mi], bfr[ni], acc[mi][ni]);
    __syncthreads();
  }

  // epilogue: C row = m0+wr*64+mi*16+lr*4+r, col = n0+wc*64+ni*16+lc
#pragma unroll
  for (int mi = 0; mi < 4; mi++) {
#pragma unroll
    for (int ni = 0; ni < 4; ni++) {
      const int col = n0 + wc * 64 + ni * 16 + lc;
      const int rowb = m0 + wr * 64 + mi * 16 + lr * 4;
      if (MODE == 0) {
        const int qkv = col / 768;  // uniform per fragment (768 = 48*16)
        const int rem = col - qkv * 768;
        const int h = rem >> 6, d = rem & 63, fi = d >> 1;
        const float bb = (qkv == 0 ? bQ : qkv == 1 ? bK : bV)[rem];
#pragma unroll
        for (int r = 0; r < 4; r++) {
          const int grow = rowb + r;
          const int t = grow & 2047;
          float v = acc[mi][ni][r] + bb;
          float pv = __shfl_xor(v, 1);  // partner of the rope pair (adjacent col)
          if (qkv < 2) {
            const float c = cost[t * 32 + fi], s = sint[t * 32 + fi];
            float o = (d & 1) ? (pv * s + v * c) : (v * c - pv * s);
            if (qkv == 0) o *= 0.125f;  // fold 1/sqrt(64) into Q
            (qkv == 0 ? Qb : Kb)[(size_t)grow * 768 + rem] = f2bf(o);
          } else {
            const int bidx = grow >> 11;
            Vt[((size_t)(bidx * 12 + h) * 64 + d) * 2048 + t] = f2bf(v);
          }
        }
      } else {
        const float bb = bO[col];
#pragma unroll
        for (int r = 0; r < 4; r++) {
          const int grow = rowb + r;
          Out[(size_t)grow * 768 + col] = acc[mi][ni][r] + bb;
        }
      }
    }
  }
}

// ---------------- causal flash attention ----------------
// grid (32 qblocks, 24 bh), 256 threads = 4 waves, each wave owns 16 q rows.
// Qb/Kb: [B][T][768] bf16 (Q pre-scaled by 1/8, both roped). Vt: [bh][64][2048] bf16.
__global__ __launch_bounds__(256) void attn_kernel(
    const u16* __restrict__ Qb, const u16* __restrict__ Kb,
    const u16* __restrict__ Vt, u16* __restrict__ Ob) {
  __shared__ u16 Plds[4 * 16 * 64];  // per-wave P^T staging [16 q][64 k]
  const int qblk = blockIdx.x, bh = blockIdx.y;
  const int b = bh / 12, h = bh - b * 12;
  const int tid = threadIdx.x, w = tid >> 6, l = tid & 63;
  const int lr = l >> 4, lc = l & 15;
  const int q0 = qblk * 64;
  const int qw = q0 + w * 16;

  // Q fragments (A-operand): row = lc, k(d) = chunk*32 + lr*8
  bf16x8 aq0, aq1;
  {
    const u16* qp = Qb + ((size_t)(b * 2048 + qw + lc)) * 768 + h * 64 + lr * 8;
    aq0 = *(const bf16x8*)qp;
    aq1 = *(const bf16x8*)(qp + 32);
  }

  float m_run[4], l_run[4];
  f32x4 acc[4];
#pragma unroll
  for (int r = 0; r < 4; r++) { m_run[r] = -INFINITY; l_run[r] = 0.f; }
#pragma unroll
  for (int dt = 0; dt < 4; dt++) acc[dt] = (f32x4){0.f, 0.f, 0.f, 0.f};

  u16* pw = &Plds[w * 1024];

  for (int kv = 0; kv <= qblk; kv++) {
    const int kv0 = kv * 64;
    f32x4 s[4];
#pragma unroll
    for (int kt = 0; kt < 4; kt++) {
      const u16* kp = Kb + ((size_t)(b * 2048 + kv0 + kt * 16 + lc)) * 768 + h * 64 + lr * 8;
      bf16x8 bk0 = *(const bf16x8*)kp;
      bf16x8 bk1 = *(const bf16x8*)(kp + 32);
      f32x4 sv = (f32x4){0.f, 0.f, 0.f, 0.f};
      sv = MFMA(aq0, bk0, sv);
      sv = MFMA(aq1, bk1, sv);
      s[kt] = sv;
    }
    if (kv == qblk) {  // causal mask inside diagonal tile
#pragma unroll
      for (int kt = 0; kt < 4; kt++)
#pragma unroll
        for (int r = 0; r < 4; r++)
          s[kt][r] = (kv0 + kt * 16 + lc > qw + lr * 4 + r) ? -INFINITY : s[kt][r];
    }
    // per-row max across 4 key-subtiles (in-lane) then across 16 col-lanes
    float pm[4];
#pragma unroll
    for (int r = 0; r < 4; r++)
      pm[r] = fmaxf(fmaxf(s[0][r], s[1][r]), fmaxf(s[2][r], s[3][r]));
#pragma unroll
    for (int st = 1; st < 16; st <<= 1)
#pragma unroll
      for (int r = 0; r < 4; r++) pm[r] = fmaxf(pm[r], __shfl_xor(pm[r], st));

    float alpha[4], rs[4];
#pragma unroll
    for (int r = 0; r < 4; r++) {
      float mn = fmaxf(m_run[r], pm[r]);
      alpha[r] = __expf(m_run[r] - mn);
      m_run[r] = mn;
      rs[r] = 0.f;
    }
    // P = exp(S - m), store bf16 to per-wave LDS (transpose for PV A-operand)
#pragma unroll
    for (int kt = 0; kt < 4; kt++)
#pragma unroll
      for (int r = 0; r < 4; r++) {
        float p = __expf(s[kt][r] - m_run[r]);
        rs[r] += p;
        pw[(lr * 4 + r) * 64 + kt * 16 + lc] = f2bf(p);
      }
#pragma unroll
    for (int st = 1; st < 16; st <<= 1)
#pragma unroll
      for (int r = 0; r < 4; r++) rs[r] += __shfl_xor(rs[r], st);
#pragma unroll
    for (int r = 0; r < 4; r++) l_run[r] = l_run[r] * alpha[r] + rs[r];
#pragma unroll
    for (int dt = 0; dt < 4; dt++) {
      acc[dt][0] *= alpha[0]; acc[dt][1] *= alpha[1];
      acc[dt][2] *= alpha[2]; acc[dt][3] *= alpha[3];
    }
    __syncthreads();
    // P A-fragments: row(q) = lc, k(key) = kc*32 + lr*8
    bf16x8 pa0 = *(const bf16x8*)&pw[lc * 64 + lr * 8];
    bf16x8 pa1 = *(const bf16x8*)&pw[lc * 64 + 32 + lr * 8];
#pragma unroll
    for (int dt = 0; dt < 4; dt++) {
      const u16* vp = Vt + ((size_t)(bh * 64 + dt * 16 + lc)) * 2048 + kv0 + lr * 8;
      bf16x8 bv0 = *(const bf16x8*)vp;
      bf16x8 bv1 = *(const bf16x8*)(vp + 32);
      acc[dt] = MFMA(pa0, bv0, acc[dt]);
      acc[dt] = MFMA(pa1, bv1, acc[dt]);
    }
    __syncthreads();
  }

#pragma unroll
  for (int dt = 0; dt < 4; dt++)
#pragma unroll
    for (int r = 0; r < 4; r++) {
      const int q = qw + lr * 4 + r;
      float o = acc[dt][r] / l_run[r];
      Ob[((size_t)(b * 2048 + q)) * 768 + h * 64 + dt * 16 + lc] = f2bf(o);
    }
}

// ---------------- launcher ----------------

extern "C" void kernel_launch(void* const* d_in, const int* in_sizes, int n_in,
                              void* d_out, int out_size, void* d_ws, size_t ws_size,
                              hipStream_t stream) {
  const float* x  = (const float*)d_in[0];
  const float* WQ = (const float*)d_in[1];
  const float* bQ = (const float*)d_in[2];
  const float* WK = (const float*)d_in[3];
  const float* bK = (const float*)d_in[4];
  const float* WV = (const float*)d_in[5];
  const float* bV = (const float*)d_in[6];
  const float* WO = (const float*)d_in[7];
  const float* bO = (const float*)d_in[8];

  char* ws = (char*)d_ws;
  u16* Xb    = (u16*)(ws + 0);          // 4096x768 bf16
  u16* Wqkv  = (u16*)(ws + 6291456);    // 2304x768 bf16 (B^T)
  u16* WoT   = (u16*)(ws + 9830400);    // 768x768 bf16 (B^T)
  u16* Qb    = (u16*)(ws + 11010048);   // [B][T][768] bf16
  u16* Kb    = (u16*)(ws + 17301504);   // [B][T][768] bf16
  u16* Vt    = (u16*)(ws + 23592960);   // [bh][64][2048] bf16
  u16* Ob    = (u16*)(ws + 29884416);   // [B*T][768] bf16
  float* cost = (float*)(ws + 36175872); // [2048][32]
  float* sint = (float*)(ws + 36438016); // [2048][32]

  rope_tables<<<256, 256, 0, stream>>>(cost, sint);
  cast_x<<<3072, 256, 0, stream>>>(x, Xb, 4096 * 768);
  prep_wqkv<<<dim3(24, 2, 36), dim3(32, 8), 0, stream>>>(WQ, WK, WV, Wqkv);
  prep_wo<<<dim3(24, 24), dim3(32, 8), 0, stream>>>(WO, WoT);

  gemm_bt<0><<<dim3(32, 18), 256, 0, stream>>>(Xb, Wqkv, 768, 768, 768,
                                               bQ, bK, bV, cost, sint,
                                               Qb, Kb, Vt, nullptr, nullptr);
  attn_kernel<<<dim3(32, 24), 256, 0, stream>>>(Qb, Kb, Vt, Ob);
  gemm_bt<1><<<dim3(32, 6), 256, 0, stream>>>(Ob, WoT, 768, 768, 768,
                                              nullptr, nullptr, nullptr, nullptr, nullptr,
                                              nullptr, nullptr, nullptr, bO, (float*)d_out);
}

// Round 2
// 250.247 us; speedup vs baseline: 1.0236x; 1.0236x over previous
//
#include <hip/hip_runtime.h>

typedef unsigned short u16;
typedef short bf16x8 __attribute__((ext_vector_type(8)));
typedef float f32x4 __attribute__((ext_vector_type(4)));

#define MFMA(a, b, c) __builtin_amdgcn_mfma_f32_16x16x32_bf16(a, b, c, 0, 0, 0)

// f32 -> bf16 round-to-nearest-even
__device__ __forceinline__ u16 f2bf(float f) {
  unsigned int u = __float_as_uint(f);
  u = (u + 0x7FFFu + ((u >> 16) & 1u)) >> 16;
  return (u16)u;
}

// async global->LDS, 16B per lane; lds dest must be wave-uniform base (HW adds lane*16)
#define GLOAD16(gp, lp)                                                        \
  __builtin_amdgcn_global_load_lds(                                            \
      (const __attribute__((address_space(1))) void*)(gp),                     \
      (__attribute__((address_space(3))) void*)(lp), 16, 0, 0)

// ---------------- prep kernels ----------------

__global__ void rope_tables(float* __restrict__ cost, float* __restrict__ sint) {
  int idx = blockIdx.x * 256 + threadIdx.x;
  if (idx >= 2048 * 32) return;
  int t = idx >> 5, i = idx & 31;
  float invf = expf(-(float)i * 0.28782313662425572f);
  float ang = (float)t * invf;
  cost[idx] = cosf(ang);
  sint[idx] = sinf(ang);
}

__global__ void cast_x(const float* __restrict__ x, u16* __restrict__ xb, int n) {
  int i = (blockIdx.x * 256 + threadIdx.x) * 4;
  if (i >= n) return;
  float4 v = *(const float4*)(x + i);
  u16 o0 = f2bf(v.x), o1 = f2bf(v.y), o2 = f2bf(v.z), o3 = f2bf(v.w);
  ushort4 o = make_ushort4(o0, o1, o2, o3);
  *(ushort4*)(xb + i) = o;
}

// Wqkv_t[qkv*768 + h*64 + d][c] = W_{qkv}[h][c][d]   (bf16, B^T layout for GEMM)
__global__ void prep_wqkv(const float* __restrict__ WQ, const float* __restrict__ WK,
                          const float* __restrict__ WV, u16* __restrict__ Wt) {
  __shared__ float tile[32][33];
  const int z = blockIdx.z;              // 0..35
  const int qkv = z / 12, h = z - qkv * 12;
  const float* W = (qkv == 0 ? WQ : qkv == 1 ? WK : WV) + (size_t)h * 768 * 64;
  const int k0 = blockIdx.x * 32, d0 = blockIdx.y * 32;
  const int tx = threadIdx.x, ty = threadIdx.y;
#pragma unroll
  for (int it = 0; it < 4; it++)
    tile[ty + it * 8][tx] = W[(size_t)(k0 + ty + it * 8) * 64 + d0 + tx];
  __syncthreads();
  u16* out = Wt + (size_t)(qkv * 768 + h * 64 + d0) * 768 + k0;
#pragma unroll
  for (int it = 0; it < 4; it++)
    out[(size_t)(ty + it * 8) * 768 + tx] = f2bf(tile[tx][ty + it * 8]);
}

// WoT[m][hd] = W_O[hd][m]  (768x768 transpose, bf16)
__global__ void prep_wo(const float* __restrict__ WO, u16* __restrict__ Wt) {
  __shared__ float tile[32][33];
  const int a0 = blockIdx.x * 32, m0 = blockIdx.y * 32;
  const int tx = threadIdx.x, ty = threadIdx.y;
#pragma unroll
  for (int it = 0; it < 4; it++)
    tile[ty + it * 8][tx] = WO[(size_t)(a0 + ty + it * 8) * 768 + m0 + tx];
  __syncthreads();
#pragma unroll
  for (int it = 0; it < 4; it++)
    Wt[(size_t)(m0 + ty + it * 8) * 768 + a0 + tx] = f2bf(tile[tx][ty + it * 8]);
}

// ---------------- GEMM (128x128 tile, BK=32, 4 waves, 16x16x32 bf16 MFMA) ----------------
template <int MODE>
__global__ __launch_bounds__(256) void gemm_bt(
    const u16* __restrict__ A, const u16* __restrict__ Bt, int K, int LDA, int LDB,
    const float* __restrict__ bQ, const float* __restrict__ bK, const float* __restrict__ bV,
    const float* __restrict__ cost, const float* __restrict__ sint,
    u16* __restrict__ Qb, u16* __restrict__ Kb, u16* __restrict__ Vt,
    const float* __restrict__ bO, float* __restrict__ Out) {
  __shared__ u16 As[128 * 32];
  __shared__ u16 Bs[128 * 32];
  const int tid = threadIdx.x;
  const int w = tid >> 6, l = tid & 63;
  const int lr = l >> 4, lc = l & 15;
  const int wr = w >> 1, wc = w & 1;
  const int m0 = blockIdx.x * 128, n0 = blockIdx.y * 128;

  f32x4 acc[4][4];
#pragma unroll
  for (int mi = 0; mi < 4; mi++)
#pragma unroll
    for (int ni = 0; ni < 4; ni++) acc[mi][ni] = (f32x4){0.f, 0.f, 0.f, 0.f};

  for (int kt = 0; kt < K; kt += 32) {
    const u16* ga = A + (size_t)(m0 + w * 16 + (l >> 2)) * LDA + kt + (l & 3) * 8;
    const u16* gb = Bt + (size_t)(n0 + w * 16 + (l >> 2)) * LDB + kt + (l & 3) * 8;
    GLOAD16(ga, &As[w * 512]);
    GLOAD16(ga + (size_t)64 * LDA, &As[2048 + w * 512]);
    GLOAD16(gb, &Bs[w * 512]);
    GLOAD16(gb + (size_t)64 * LDB, &Bs[2048 + w * 512]);
    __syncthreads();

    bf16x8 af[4], bfr[4];
#pragma unroll
    for (int mi = 0; mi < 4; mi++)
      af[mi] = *(const bf16x8*)&As[(wr * 64 + mi * 16 + lc) * 32 + lr * 8];
#pragma unroll
    for (int ni = 0; ni < 4; ni++)
      bfr[ni] = *(const bf16x8*)&Bs[(wc * 64 + ni * 16 + lc) * 32 + lr * 8];
#pragma unroll
    for (int mi = 0; mi < 4; mi++)
#pragma unroll
      for (int ni = 0; ni < 4; ni++)
        acc[mi][ni] = MFMA(af[mi], bfr[ni], acc[mi][ni]);
    __syncthreads();
  }

#pragma unroll
  for (int mi = 0; mi < 4; mi++) {
#pragma unroll
    for (int ni = 0; ni < 4; ni++) {
      const int col = n0 + wc * 64 + ni * 16 + lc;
      const int rowb = m0 + wr * 64 + mi * 16 + lr * 4;
      if (MODE == 0) {
        const int qkv = col / 768;  // uniform per fragment (768 = 48*16)
        const int rem = col - qkv * 768;
        const int h = rem >> 6, d = rem & 63, fi = d >> 1;
        const float bb = (qkv == 0 ? bQ : qkv == 1 ? bK : bV)[rem];
#pragma unroll
        for (int r = 0; r < 4; r++) {
          const int grow = rowb + r;
          const int t = grow & 2047;
          float v = acc[mi][ni][r] + bb;
          float pv = __shfl_xor(v, 1);  // partner of the rope pair (adjacent col)
          if (qkv < 2) {
            const float c = cost[t * 32 + fi], s = sint[t * 32 + fi];
            float o = (d & 1) ? (pv * s + v * c) : (v * c - pv * s);
            if (qkv == 0) o *= 0.125f;  // fold 1/sqrt(64) into Q
            (qkv == 0 ? Qb : Kb)[(size_t)grow * 768 + rem] = f2bf(o);
          } else {
            const int bidx = grow >> 11;
            Vt[((size_t)(bidx * 12 + h) * 64 + d) * 2048 + t] = f2bf(v);
          }
        }
      } else {
        const float bb = bO[col];
#pragma unroll
        for (int r = 0; r < 4; r++) {
          const int grow = rowb + r;
          Out[(size_t)grow * 768 + col] = acc[mi][ni][r] + bb;
        }
      }
    }
  }
}

// ---------------- causal flash attention (no block barriers, wave-private) ----------------
// grid (32 qblocks desc, 24 bh), 4 waves, each wave owns 16 q rows.
// Qb/Kb: [B][T][768] bf16 (Q pre-scaled by 1/8, both roped). Vt: [bh][64][2048] bf16.
// P staging LDS is per-wave + double-buffered; only intra-wave lgkmcnt ordering needed.
// P row stride = 128B -> XOR-swizzle byte^=((row&7)<<4) kills the 16-way read conflict.
__global__ __launch_bounds__(256) void attn_kernel(
    const u16* __restrict__ Qb, const u16* __restrict__ Kb,
    const u16* __restrict__ Vt, u16* __restrict__ Ob) {
  __shared__ u16 Plds[2 * 4 * 16 * 64];  // [dbuf][wave][16 q][64 k]
  const int qblk = 31 - blockIdx.x;      // longest blocks dispatched first
  const int bh = blockIdx.y;
  const int b = bh / 12, h = bh - b * 12;
  const int tid = threadIdx.x, w = tid >> 6, l = tid & 63;
  const int lr = l >> 4, lc = l & 15;
  const int qw = qblk * 64 + w * 16;

  // Q fragments (A-operand): row = lc, k(d) = chunk*32 + lr*8
  const u16* qp = Qb + ((size_t)(b * 2048 + qw + lc)) * 768 + h * 64 + lr * 8;
  bf16x8 aq0 = *(const bf16x8*)qp;
  bf16x8 aq1 = *(const bf16x8*)(qp + 32);

  float m_run[4], l_run[4];
  f32x4 acc[4];
#pragma unroll
  for (int r = 0; r < 4; r++) { m_run[r] = -INFINITY; l_run[r] = 0.f; }
#pragma unroll
  for (int dt = 0; dt < 4; dt++) acc[dt] = (f32x4){0.f, 0.f, 0.f, 0.f};

  char* pwb = (char*)Plds + w * 2048;  // per-wave 2KB region (x2 buffers at +8192)
  const u16* kbase = Kb + (size_t)(b * 2048) * 768 + h * 64;
  const u16* vbase = Vt + (size_t)(bh * 64) * 2048;

  // prefetch K tile 0 into registers
  bf16x8 kc[4][2];
#pragma unroll
  for (int kt = 0; kt < 4; kt++) {
    const u16* kp = kbase + (size_t)(kt * 16 + lc) * 768 + lr * 8;
    kc[kt][0] = *(const bf16x8*)kp;
    kc[kt][1] = *(const bf16x8*)(kp + 32);
  }

  for (int kv = 0; kv <= qblk; kv++) {
    const int kv0 = kv * 64;
    char* pcur = pwb + ((kv & 1) << 13);

    // V loads for this tile -- issued BEFORE the asm clobber so they fly
    // under the whole softmax chain
    bf16x8 bv[4][2];
#pragma unroll
    for (int dt = 0; dt < 4; dt++) {
      const u16* vp = vbase + (size_t)(dt * 16 + lc) * 2048 + kv0 + lr * 8;
      bv[dt][0] = *(const bf16x8*)vp;
      bv[dt][1] = *(const bf16x8*)(vp + 32);
    }

    // S = Q K^T on the prefetched K registers
    f32x4 s[4];
#pragma unroll
    for (int kt = 0; kt < 4; kt++) {
      f32x4 sv = (f32x4){0.f, 0.f, 0.f, 0.f};
      sv = MFMA(aq0, kc[kt][0], sv);
      sv = MFMA(aq1, kc[kt][1], sv);
      s[kt] = sv;
    }

    // prefetch next K tile (in flight during softmax + PV)
    if (kv < qblk) {
#pragma unroll
      for (int kt = 0; kt < 4; kt++) {
        const u16* kp = kbase + (size_t)(kv0 + 64 + kt * 16 + lc) * 768 + lr * 8;
        kc[kt][0] = *(const bf16x8*)kp;
        kc[kt][1] = *(const bf16x8*)(kp + 32);
      }
    }

    if (kv == qblk) {  // causal mask inside diagonal tile
#pragma unroll
      for (int kt = 0; kt < 4; kt++)
#pragma unroll
        for (int r = 0; r < 4; r++)
          s[kt][r] = (kv0 + kt * 16 + lc > qw + lr * 4 + r) ? -INFINITY : s[kt][r];
    }

    float pm[4];
#pragma unroll
    for (int r = 0; r < 4; r++)
      pm[r] = fmaxf(fmaxf(s[0][r], s[1][r]), fmaxf(s[2][r], s[3][r]));
#pragma unroll
    for (int st = 1; st < 16; st <<= 1)
#pragma unroll
      for (int r = 0; r < 4; r++) pm[r] = fmaxf(pm[r], __shfl_xor(pm[r], st));

    float alpha[4], rs[4];
#pragma unroll
    for (int r = 0; r < 4; r++) {
      float mn = fmaxf(m_run[r], pm[r]);
      alpha[r] = __expf(m_run[r] - mn);
      m_run[r] = mn;
      rs[r] = 0.f;
    }

    // P = exp(S - m) -> swizzled per-wave LDS (bf16)
#pragma unroll
    for (int kt = 0; kt < 4; kt++)
#pragma unroll
      for (int r = 0; r < 4; r++) {
        float p = __expf(s[kt][r] - m_run[r]);
        rs[r] += p;
        const int q = lr * 4 + r;
        const int byt = q * 128 + (((kt * 16 + lc) * 2) ^ ((q & 7) << 4));
        *(u16*)(pcur + byt) = f2bf(p);
      }
#pragma unroll
    for (int st = 1; st < 16; st <<= 1)
#pragma unroll
      for (int r = 0; r < 4; r++) rs[r] += __shfl_xor(rs[r], st);
#pragma unroll
    for (int r = 0; r < 4; r++) l_run[r] = l_run[r] * alpha[r] + rs[r];
#pragma unroll
    for (int dt = 0; dt < 4; dt++) {
      acc[dt][0] *= alpha[0]; acc[dt][1] *= alpha[1];
      acc[dt][2] *= alpha[2]; acc[dt][3] *= alpha[3];
    }

    // intra-wave ordering only: drain the ds_writes, then read P fragments
    asm volatile("s_waitcnt lgkmcnt(0)" ::: "memory");
    bf16x8 pa0 = *(const bf16x8*)(pcur + lc * 128 + ((lr * 16) ^ ((lc & 7) << 4)));
    bf16x8 pa1 = *(const bf16x8*)(pcur + lc * 128 + ((64 + lr * 16) ^ ((lc & 7) << 4)));
#pragma unroll
    for (int dt = 0; dt < 4; dt++) {
      acc[dt] = MFMA(pa0, bv[dt][0], acc[dt]);
      acc[dt] = MFMA(pa1, bv[dt][1], acc[dt]);
    }
  }

#pragma unroll
  for (int dt = 0; dt < 4; dt++)
#pragma unroll
    for (int r = 0; r < 4; r++) {
      const int q = qw + lr * 4 + r;
      float o = acc[dt][r] / l_run[r];
      Ob[((size_t)(b * 2048 + q)) * 768 + h * 64 + dt * 16 + lc] = f2bf(o);
    }
}

// ---------------- launcher ----------------

extern "C" void kernel_launch(void* const* d_in, const int* in_sizes, int n_in,
                              void* d_out, int out_size, void* d_ws, size_t ws_size,
                              hipStream_t stream) {
  const float* x  = (const float*)d_in[0];
  const float* WQ = (const float*)d_in[1];
  const float* bQ = (const float*)d_in[2];
  const float* WK = (const float*)d_in[3];
  const float* bK = (const float*)d_in[4];
  const float* WV = (const float*)d_in[5];
  const float* bV = (const float*)d_in[6];
  const float* WO = (const float*)d_in[7];
  const float* bO = (const float*)d_in[8];

  char* ws = (char*)d_ws;
  u16* Xb    = (u16*)(ws + 0);          // 4096x768 bf16
  u16* Wqkv  = (u16*)(ws + 6291456);    // 2304x768 bf16 (B^T)
  u16* WoT   = (u16*)(ws + 9830400);    // 768x768 bf16 (B^T)
  u16* Qb    = (u16*)(ws + 11010048);   // [B][T][768] bf16
  u16* Kb    = (u16*)(ws + 17301504);   // [B][T][768] bf16
  u16* Vt    = (u16*)(ws + 23592960);   // [bh][64][2048] bf16
  u16* Ob    = (u16*)(ws + 29884416);   // [B*T][768] bf16
  float* cost = (float*)(ws + 36175872); // [2048][32]
  float* sint = (float*)(ws + 36438016); // [2048][32]

  rope_tables<<<256, 256, 0, stream>>>(cost, sint);
  cast_x<<<3072, 256, 0, stream>>>(x, Xb, 4096 * 768);
  prep_wqkv<<<dim3(24, 2, 36), dim3(32, 8), 0, stream>>>(WQ, WK, WV, Wqkv);
  prep_wo<<<dim3(24, 24), dim3(32, 8), 0, stream>>>(WO, WoT);

  gemm_bt<0><<<dim3(32, 18), 256, 0, stream>>>(Xb, Wqkv, 768, 768, 768,
                                               bQ, bK, bV, cost, sint,
                                               Qb, Kb, Vt, nullptr, nullptr);
  attn_kernel<<<dim3(32, 24), 256, 0, stream>>>(Qb, Kb, Vt, Ob);
  gemm_bt<1><<<dim3(32, 6), 256, 0, stream>>>(Ob, WoT, 768, 768, 768,
                                              nullptr, nullptr, nullptr, nullptr, nullptr,
                                              nullptr, nullptr, nullptr, bO, (float*)d_out);
}

// Round 3
// 162.573 us; speedup vs baseline: 1.5756x; 1.5393x over previous
//
#include <hip/hip_runtime.h>

typedef unsigned short u16;
typedef short bf16x8 __attribute__((ext_vector_type(8)));
typedef float f32x4 __attribute__((ext_vector_type(4)));

#define MFMA(a, b, c) __builtin_amdgcn_mfma_f32_16x16x32_bf16(a, b, c, 0, 0, 0)

// f32 -> bf16 round-to-nearest-even
__device__ __forceinline__ u16 f2bf(float f) {
  unsigned int u = __float_as_uint(f);
  u = (u + 0x7FFFu + ((u >> 16) & 1u)) >> 16;
  return (u16)u;
}

// async global->LDS, 16B per lane; lds dest must be wave-uniform base (HW adds lane*16)
#define GLOAD16(gp, lp)                                                        \
  __builtin_amdgcn_global_load_lds(                                            \
      (const __attribute__((address_space(1))) void*)(gp),                     \
      (__attribute__((address_space(3))) void*)(lp), 16, 0, 0)

// ---------------- prep kernels ----------------

__global__ void rope_tables(float* __restrict__ cost, float* __restrict__ sint) {
  int idx = blockIdx.x * 256 + threadIdx.x;
  if (idx >= 2048 * 32) return;
  int t = idx >> 5, i = idx & 31;
  float invf = expf(-(float)i * 0.28782313662425572f);
  float ang = (float)t * invf;
  cost[idx] = cosf(ang);
  sint[idx] = sinf(ang);
}

__global__ void cast_x(const float* __restrict__ x, u16* __restrict__ xb, int n) {
  int i = (blockIdx.x * 256 + threadIdx.x) * 4;
  if (i >= n) return;
  float4 v = *(const float4*)(x + i);
  u16 o0 = f2bf(v.x), o1 = f2bf(v.y), o2 = f2bf(v.z), o3 = f2bf(v.w);
  ushort4 o = make_ushort4(o0, o1, o2, o3);
  *(ushort4*)(xb + i) = o;
}

// Wqkv_t[qkv*768 + h*64 + d][c] = W_{qkv}[h][c][d]   (bf16, B^T layout for GEMM)
__global__ void prep_wqkv(const float* __restrict__ WQ, const float* __restrict__ WK,
                          const float* __restrict__ WV, u16* __restrict__ Wt) {
  __shared__ float tile[32][33];
  const int z = blockIdx.z;              // 0..35
  const int qkv = z / 12, h = z - qkv * 12;
  const float* W = (qkv == 0 ? WQ : qkv == 1 ? WK : WV) + (size_t)h * 768 * 64;
  const int k0 = blockIdx.x * 32, d0 = blockIdx.y * 32;
  const int tx = threadIdx.x, ty = threadIdx.y;
#pragma unroll
  for (int it = 0; it < 4; it++)
    tile[ty + it * 8][tx] = W[(size_t)(k0 + ty + it * 8) * 64 + d0 + tx];
  __syncthreads();
  u16* out = Wt + (size_t)(qkv * 768 + h * 64 + d0) * 768 + k0;
#pragma unroll
  for (int it = 0; it < 4; it++)
    out[(size_t)(ty + it * 8) * 768 + tx] = f2bf(tile[tx][ty + it * 8]);
}

// WoT[m][hd] = W_O[hd][m]  (768x768 transpose, bf16)
__global__ void prep_wo(const float* __restrict__ WO, u16* __restrict__ Wt) {
  __shared__ float tile[32][33];
  const int a0 = blockIdx.x * 32, m0 = blockIdx.y * 32;
  const int tx = threadIdx.x, ty = threadIdx.y;
#pragma unroll
  for (int it = 0; it < 4; it++)
    tile[ty + it * 8][tx] = WO[(size_t)(a0 + ty + it * 8) * 768 + m0 + tx];
  __syncthreads();
#pragma unroll
  for (int it = 0; it < 4; it++)
    Wt[(size_t)(m0 + ty + it * 8) * 768 + a0 + tx] = f2bf(tile[tx][ty + it * 8]);
}

// ---------------- GEMM (128x128 tile, BK=32, 4 waves, 16x16x32 bf16 MFMA) ----------------
template <int MODE>
__global__ __launch_bounds__(256) void gemm_bt(
    const u16* __restrict__ A, const u16* __restrict__ Bt, int K, int LDA, int LDB,
    const float* __restrict__ bQ, const float* __restrict__ bK, const float* __restrict__ bV,
    const float* __restrict__ cost, const float* __restrict__ sint,
    u16* __restrict__ Qb, u16* __restrict__ Kb, u16* __restrict__ Vt,
    const float* __restrict__ bO, float* __restrict__ Out) {
  __shared__ u16 As[128 * 32];
  __shared__ u16 Bs[128 * 32];
  const int tid = threadIdx.x;
  const int w = tid >> 6, l = tid & 63;
  const int lr = l >> 4, lc = l & 15;
  const int wr = w >> 1, wc = w & 1;
  const int m0 = blockIdx.x * 128, n0 = blockIdx.y * 128;

  f32x4 acc[4][4];
#pragma unroll
  for (int mi = 0; mi < 4; mi++)
#pragma unroll
    for (int ni = 0; ni < 4; ni++) acc[mi][ni] = (f32x4){0.f, 0.f, 0.f, 0.f};

  for (int kt = 0; kt < K; kt += 32) {
    const u16* ga = A + (size_t)(m0 + w * 16 + (l >> 2)) * LDA + kt + (l & 3) * 8;
    const u16* gb = Bt + (size_t)(n0 + w * 16 + (l >> 2)) * LDB + kt + (l & 3) * 8;
    GLOAD16(ga, &As[w * 512]);
    GLOAD16(ga + (size_t)64 * LDA, &As[2048 + w * 512]);
    GLOAD16(gb, &Bs[w * 512]);
    GLOAD16(gb + (size_t)64 * LDB, &Bs[2048 + w * 512]);
    __syncthreads();

    bf16x8 af[4], bfr[4];
#pragma unroll
    for (int mi = 0; mi < 4; mi++)
      af[mi] = *(const bf16x8*)&As[(wr * 64 + mi * 16 + lc) * 32 + lr * 8];
#pragma unroll
    for (int ni = 0; ni < 4; ni++)
      bfr[ni] = *(const bf16x8*)&Bs[(wc * 64 + ni * 16 + lc) * 32 + lr * 8];
#pragma unroll
    for (int mi = 0; mi < 4; mi++)
#pragma unroll
      for (int ni = 0; ni < 4; ni++)
        acc[mi][ni] = MFMA(af[mi], bfr[ni], acc[mi][ni]);
    __syncthreads();
  }

#pragma unroll
  for (int mi = 0; mi < 4; mi++) {
#pragma unroll
    for (int ni = 0; ni < 4; ni++) {
      const int col = n0 + wc * 64 + ni * 16 + lc;
      const int rowb = m0 + wr * 64 + mi * 16 + lr * 4;
      if (MODE == 0) {
        const int qkv = col / 768;  // uniform per fragment (768 = 48*16)
        const int rem = col - qkv * 768;
        const int h = rem >> 6, d = rem & 63, fi = d >> 1;
        const float bb = (qkv == 0 ? bQ : qkv == 1 ? bK : bV)[rem];
#pragma unroll
        for (int r = 0; r < 4; r++) {
          const int grow = rowb + r;
          const int t = grow & 2047;
          float v = acc[mi][ni][r] + bb;
          float pv = __shfl_xor(v, 1);  // partner of the rope pair (adjacent col)
          if (qkv < 2) {
            const float c = cost[t * 32 + fi], s = sint[t * 32 + fi];
            float o = (d & 1) ? (pv * s + v * c) : (v * c - pv * s);
            if (qkv == 0) o *= 0.125f;  // fold 1/sqrt(64) into Q
            (qkv == 0 ? Qb : Kb)[(size_t)grow * 768 + rem] = f2bf(o);
          } else {
            const int bidx = grow >> 11;
            Vt[((size_t)(bidx * 12 + h) * 64 + d) * 2048 + t] = f2bf(v);
          }
        }
      } else {
        const float bb = bO[col];
#pragma unroll
        for (int r = 0; r < 4; r++) {
          const int grow = rowb + r;
          Out[(size_t)grow * 768 + col] = acc[mi][ni][r] + bb;
        }
      }
    }
  }
}

// ---------------- causal flash attention ----------------
// grid (32 qblocks desc, 24 bh), 4 waves, each wave owns 16 q rows.
// K/V tiles staged in LDS via global_load_lds (zero VGPR cost), double-buffered,
// one __syncthreads per kv-iteration (its vmcnt/lgkm drain is the fence).
// Swizzle per rule #21: linear LDS dest + pre-swizzled global SOURCE column
// (col8 = (l&7)^(l>>3)) + XOR-swizzled read (byte ^= (row&7)<<4).
// P staging stays wave-private, single-buffered, swizzled.
__global__ __launch_bounds__(256) void attn_kernel(
    const u16* __restrict__ Qb, const u16* __restrict__ Kb,
    const u16* __restrict__ Vt, u16* __restrict__ Ob) {
  __shared__ char Kls[2][8192];   // [dbuf][64 key rows][128B]
  __shared__ char Vls[2][8192];   // [dbuf][64 d rows][128B]
  __shared__ char Pls[4][2048];   // per-wave [16 q][128B]
  const int qblk = 31 - blockIdx.x;  // longest blocks dispatched first
  const int bh = blockIdx.y;
  const int b = bh / 12, h = bh - b * 12;
  const int tid = threadIdx.x, w = tid >> 6, l = tid & 63;
  const int lr = l >> 4, lc = l & 15;
  const int qw = qblk * 64 + w * 16;

  const u16* kbase = Kb + (size_t)(b * 2048) * 768 + h * 64;
  const u16* vbase = Vt + (size_t)(bh * 64) * 2048;

  // staging source addressing (pre-swizzled column)
  const int srow = w * 8 + (l >> 3);        // tile-relative row (this wave's op0)
  const int scol8 = (l & 7) ^ (l >> 3);     // 16B granule within the 128B row
  const u16* ksrc0 = kbase + (size_t)srow * 768 + scol8 * 8;
  const u16* ksrc1 = kbase + (size_t)(srow + 32) * 768 + scol8 * 8;
  const u16* vsrc0 = vbase + (size_t)srow * 2048 + scol8 * 8;
  const u16* vsrc1 = vbase + (size_t)(srow + 32) * 2048 + scol8 * 8;

#define STAGE(t, bi)                                                   \
  {                                                                    \
    const size_t ko = (size_t)(t) * 64 * 768;                          \
    const int vo = (t) * 64;                                           \
    GLOAD16(ksrc0 + ko, &Kls[bi][w * 1024]);                           \
    GLOAD16(ksrc1 + ko, &Kls[bi][4096 + w * 1024]);                    \
    GLOAD16(vsrc0 + vo, &Vls[bi][w * 1024]);                           \
    GLOAD16(vsrc1 + vo, &Vls[bi][4096 + w * 1024]);                    \
  }

  // Q fragments (A-operand): row = lc, k(d) = chunk*32 + lr*8
  const u16* qp = Qb + ((size_t)(b * 2048 + qw + lc)) * 768 + h * 64 + lr * 8;
  bf16x8 aq0 = *(const bf16x8*)qp;
  bf16x8 aq1 = *(const bf16x8*)(qp + 32);

  float m_run[4], l_run[4];
  f32x4 acc[4];
#pragma unroll
  for (int r = 0; r < 4; r++) { m_run[r] = -INFINITY; l_run[r] = 0.f; }
#pragma unroll
  for (int dt = 0; dt < 4; dt++) acc[dt] = (f32x4){0.f, 0.f, 0.f, 0.f};

  char* pw = Pls[w];
  const int swz = (lc & 7) << 4;

  STAGE(0, 0);
  __syncthreads();

  for (int kv = 0; kv <= qblk; kv++) {
    const int kv0 = kv * 64;
    const int cur = kv & 1;
    if (kv < qblk) STAGE(kv + 1, cur ^ 1);

    // S = Q K^T from LDS K tile
    f32x4 s[4];
#pragma unroll
    for (int kt = 0; kt < 4; kt++) {
      const char* kb_ = &Kls[cur][(kt * 16 + lc) * 128];
      bf16x8 bk0 = *(const bf16x8*)(kb_ + ((lr * 16) ^ swz));
      bf16x8 bk1 = *(const bf16x8*)(kb_ + ((64 + lr * 16) ^ swz));
      f32x4 sv = (f32x4){0.f, 0.f, 0.f, 0.f};
      sv = MFMA(aq0, bk0, sv);
      sv = MFMA(aq1, bk1, sv);
      s[kt] = sv;
    }

    if (kv == qblk) {  // causal mask inside diagonal tile
#pragma unroll
      for (int kt = 0; kt < 4; kt++)
#pragma unroll
        for (int r = 0; r < 4; r++)
          s[kt][r] = (kv0 + kt * 16 + lc > qw + lr * 4 + r) ? -INFINITY : s[kt][r];
    }

    float pm[4];
#pragma unroll
    for (int r = 0; r < 4; r++)
      pm[r] = fmaxf(fmaxf(s[0][r], s[1][r]), fmaxf(s[2][r], s[3][r]));
#pragma unroll
    for (int st = 1; st < 16; st <<= 1)
#pragma unroll
      for (int r = 0; r < 4; r++) pm[r] = fmaxf(pm[r], __shfl_xor(pm[r], st));

    float alpha[4], rs[4];
#pragma unroll
    for (int r = 0; r < 4; r++) {
      float mn = fmaxf(m_run[r], pm[r]);
      alpha[r] = __expf(m_run[r] - mn);
      m_run[r] = mn;
      rs[r] = 0.f;
    }

    // P = exp(S - m) -> swizzled per-wave LDS (bf16)
#pragma unroll
    for (int kt = 0; kt < 4; kt++)
#pragma unroll
      for (int r = 0; r < 4; r++) {
        float p = __expf(s[kt][r] - m_run[r]);
        rs[r] += p;
        const int q = lr * 4 + r;
        *(u16*)(pw + q * 128 + (((kt * 16 + lc) * 2) ^ ((q & 7) << 4))) = f2bf(p);
      }
#pragma unroll
    for (int st = 1; st < 16; st <<= 1)
#pragma unroll
      for (int r = 0; r < 4; r++) rs[r] += __shfl_xor(rs[r], st);
#pragma unroll
    for (int r = 0; r < 4; r++) l_run[r] = l_run[r] * alpha[r] + rs[r];
#pragma unroll
    for (int dt = 0; dt < 4; dt++) {
      acc[dt][0] *= alpha[0]; acc[dt][1] *= alpha[1];
      acc[dt][2] *= alpha[2]; acc[dt][3] *= alpha[3];
    }

    // drain P ds_writes (intra-wave), then read P fragments
    asm volatile("s_waitcnt lgkmcnt(0)" ::: "memory");
    bf16x8 pa0 = *(const bf16x8*)(pw + lc * 128 + ((lr * 16) ^ swz));
    bf16x8 pa1 = *(const bf16x8*)(pw + lc * 128 + ((64 + lr * 16) ^ swz));
#pragma unroll
    for (int dt = 0; dt < 4; dt++) {
      const char* vb_ = &Vls[cur][(dt * 16 + lc) * 128];
      bf16x8 bv0 = *(const bf16x8*)(vb_ + ((lr * 16) ^ swz));
      bf16x8 bv1 = *(const bf16x8*)(vb_ + ((64 + lr * 16) ^ swz));
      acc[dt] = MFMA(pa0, bv0, acc[dt]);
      acc[dt] = MFMA(pa1, bv1, acc[dt]);
    }

    if (kv < qblk) __syncthreads();  // next tile staged + everyone done with cur
  }

  float inv[4];
#pragma unroll
  for (int r = 0; r < 4; r++) inv[r] = 1.0f / l_run[r];
#pragma unroll
  for (int dt = 0; dt < 4; dt++)
#pragma unroll
    for (int r = 0; r < 4; r++) {
      const int q = qw + lr * 4 + r;
      Ob[((size_t)(b * 2048 + q)) * 768 + h * 64 + dt * 16 + lc] = f2bf(acc[dt][r] * inv[r]);
    }
#undef STAGE
}

// ---------------- launcher ----------------

extern "C" void kernel_launch(void* const* d_in, const int* in_sizes, int n_in,
                              void* d_out, int out_size, void* d_ws, size_t ws_size,
                              hipStream_t stream) {
  const float* x  = (const float*)d_in[0];
  const float* WQ = (const float*)d_in[1];
  const float* bQ = (const float*)d_in[2];
  const float* WK = (const float*)d_in[3];
  const float* bK = (const float*)d_in[4];
  const float* WV = (const float*)d_in[5];
  const float* bV = (const float*)d_in[6];
  const float* WO = (const float*)d_in[7];
  const float* bO = (const float*)d_in[8];

  char* ws = (char*)d_ws;
  u16* Xb    = (u16*)(ws + 0);          // 4096x768 bf16
  u16* Wqkv  = (u16*)(ws + 6291456);    // 2304x768 bf16 (B^T)
  u16* WoT   = (u16*)(ws + 9830400);    // 768x768 bf16 (B^T)
  u16* Qb    = (u16*)(ws + 11010048);   // [B][T][768] bf16
  u16* Kb    = (u16*)(ws + 17301504);   // [B][T][768] bf16
  u16* Vt    = (u16*)(ws + 23592960);   // [bh][64][2048] bf16
  u16* Ob    = (u16*)(ws + 29884416);   // [B*T][768] bf16
  float* cost = (float*)(ws + 36175872); // [2048][32]
  float* sint = (float*)(ws + 36438016); // [2048][32]

  rope_tables<<<256, 256, 0, stream>>>(cost, sint);
  cast_x<<<3072, 256, 0, stream>>>(x, Xb, 4096 * 768);
  prep_wqkv<<<dim3(24, 2, 36), dim3(32, 8), 0, stream>>>(WQ, WK, WV, Wqkv);
  prep_wo<<<dim3(24, 24), dim3(32, 8), 0, stream>>>(WO, WoT);

  gemm_bt<0><<<dim3(32, 18), 256, 0, stream>>>(Xb, Wqkv, 768, 768, 768,
                                               bQ, bK, bV, cost, sint,
                                               Qb, Kb, Vt, nullptr, nullptr);
  attn_kernel<<<dim3(32, 24), 256, 0, stream>>>(Qb, Kb, Vt, Ob);
  gemm_bt<1><<<dim3(32, 6), 256, 0, stream>>>(Ob, WoT, 768, 768, 768,
                                              nullptr, nullptr, nullptr, nullptr, nullptr,
                                              nullptr, nullptr, nullptr, bO, (float*)d_out);
}

// Round 4
// 141.437 us; speedup vs baseline: 1.8110x; 1.1494x over previous
//
#include <hip/hip_runtime.h>

typedef unsigned short u16;
typedef short bf16x8 __attribute__((ext_vector_type(8)));
typedef float f32x4 __attribute__((ext_vector_type(4)));

#define MFMA(a, b, c) __builtin_amdgcn_mfma_f32_16x16x32_bf16(a, b, c, 0, 0, 0)

// f32 -> bf16 round-to-nearest-even
__device__ __forceinline__ u16 f2bf(float f) {
  unsigned int u = __float_as_uint(f);
  u = (u + 0x7FFFu + ((u >> 16) & 1u)) >> 16;
  return (u16)u;
}

// async global->LDS, 16B per lane; lds dest must be wave-uniform base (HW adds lane*16)
#define GLOAD16(gp, lp)                                                        \
  __builtin_amdgcn_global_load_lds(                                            \
      (const __attribute__((address_space(1))) void*)(gp),                     \
      (__attribute__((address_space(3))) void*)(lp), 16, 0, 0)

// ---------------- prep kernels ----------------

__global__ void rope_tables(float* __restrict__ cost, float* __restrict__ sint) {
  int idx = blockIdx.x * 256 + threadIdx.x;
  if (idx >= 2048 * 32) return;
  int t = idx >> 5, i = idx & 31;
  float invf = expf(-(float)i * 0.28782313662425572f);
  float ang = (float)t * invf;
  cost[idx] = cosf(ang);
  sint[idx] = sinf(ang);
}

__global__ void cast_x(const float* __restrict__ x, u16* __restrict__ xb, int n) {
  int i = (blockIdx.x * 256 + threadIdx.x) * 4;
  if (i >= n) return;
  float4 v = *(const float4*)(x + i);
  u16 o0 = f2bf(v.x), o1 = f2bf(v.y), o2 = f2bf(v.z), o3 = f2bf(v.w);
  ushort4 o = make_ushort4(o0, o1, o2, o3);
  *(ushort4*)(xb + i) = o;
}

// Wqkv_t[qkv*768 + h*64 + d][c] = W_{qkv}[h][c][d]   (bf16, B^T layout for GEMM)
__global__ void prep_wqkv(const float* __restrict__ WQ, const float* __restrict__ WK,
                          const float* __restrict__ WV, u16* __restrict__ Wt) {
  __shared__ float tile[32][33];
  const int z = blockIdx.z;              // 0..35
  const int qkv = z / 12, h = z - qkv * 12;
  const float* W = (qkv == 0 ? WQ : qkv == 1 ? WK : WV) + (size_t)h * 768 * 64;
  const int k0 = blockIdx.x * 32, d0 = blockIdx.y * 32;
  const int tx = threadIdx.x, ty = threadIdx.y;
#pragma unroll
  for (int it = 0; it < 4; it++)
    tile[ty + it * 8][tx] = W[(size_t)(k0 + ty + it * 8) * 64 + d0 + tx];
  __syncthreads();
  u16* out = Wt + (size_t)(qkv * 768 + h * 64 + d0) * 768 + k0;
#pragma unroll
  for (int it = 0; it < 4; it++)
    out[(size_t)(ty + it * 8) * 768 + tx] = f2bf(tile[tx][ty + it * 8]);
}

// WoT[m][hd] = W_O[hd][m]  (768x768 transpose, bf16)
__global__ void prep_wo(const float* __restrict__ WO, u16* __restrict__ Wt) {
  __shared__ float tile[32][33];
  const int a0 = blockIdx.x * 32, m0 = blockIdx.y * 32;
  const int tx = threadIdx.x, ty = threadIdx.y;
#pragma unroll
  for (int it = 0; it < 4; it++)
    tile[ty + it * 8][tx] = WO[(size_t)(a0 + ty + it * 8) * 768 + m0 + tx];
  __syncthreads();
#pragma unroll
  for (int it = 0; it < 4; it++)
    Wt[(size_t)(m0 + ty + it * 8) * 768 + a0 + tx] = f2bf(tile[tx][ty + it * 8]);
}

// ---------------- GEMM (128x128 tile, BK=32, 4 waves, 16x16x32 bf16 MFMA) ----------------
template <int MODE>
__global__ __launch_bounds__(256) void gemm_bt(
    const u16* __restrict__ A, const u16* __restrict__ Bt, int K, int LDA, int LDB,
    const float* __restrict__ bQ, const float* __restrict__ bK, const float* __restrict__ bV,
    const float* __restrict__ cost, const float* __restrict__ sint,
    u16* __restrict__ Qb, u16* __restrict__ Kb, u16* __restrict__ Vt,
    const float* __restrict__ bO, float* __restrict__ Out) {
  __shared__ u16 As[128 * 32];
  __shared__ u16 Bs[128 * 32];
  const int tid = threadIdx.x;
  const int w = tid >> 6, l = tid & 63;
  const int lr = l >> 4, lc = l & 15;
  const int wr = w >> 1, wc = w & 1;
  const int m0 = blockIdx.x * 128, n0 = blockIdx.y * 128;

  f32x4 acc[4][4];
#pragma unroll
  for (int mi = 0; mi < 4; mi++)
#pragma unroll
    for (int ni = 0; ni < 4; ni++) acc[mi][ni] = (f32x4){0.f, 0.f, 0.f, 0.f};

  for (int kt = 0; kt < K; kt += 32) {
    const u16* ga = A + (size_t)(m0 + w * 16 + (l >> 2)) * LDA + kt + (l & 3) * 8;
    const u16* gb = Bt + (size_t)(n0 + w * 16 + (l >> 2)) * LDB + kt + (l & 3) * 8;
    GLOAD16(ga, &As[w * 512]);
    GLOAD16(ga + (size_t)64 * LDA, &As[2048 + w * 512]);
    GLOAD16(gb, &Bs[w * 512]);
    GLOAD16(gb + (size_t)64 * LDB, &Bs[2048 + w * 512]);
    __syncthreads();

    bf16x8 af[4], bfr[4];
#pragma unroll
    for (int mi = 0; mi < 4; mi++)
      af[mi] = *(const bf16x8*)&As[(wr * 64 + mi * 16 + lc) * 32 + lr * 8];
#pragma unroll
    for (int ni = 0; ni < 4; ni++)
      bfr[ni] = *(const bf16x8*)&Bs[(wc * 64 + ni * 16 + lc) * 32 + lr * 8];
#pragma unroll
    for (int mi = 0; mi < 4; mi++)
#pragma unroll
      for (int ni = 0; ni < 4; ni++)
        acc[mi][ni] = MFMA(af[mi], bfr[ni], acc[mi][ni]);
    __syncthreads();
  }

#pragma unroll
  for (int mi = 0; mi < 4; mi++) {
#pragma unroll
    for (int ni = 0; ni < 4; ni++) {
      const int col = n0 + wc * 64 + ni * 16 + lc;
      const int rowb = m0 + wr * 64 + mi * 16 + lr * 4;
      if (MODE == 0) {
        const int qkv = col / 768;  // uniform per fragment (768 = 48*16)
        const int rem = col - qkv * 768;
        const int h = rem >> 6, d = rem & 63, fi = d >> 1;
        const float bb = (qkv == 0 ? bQ : qkv == 1 ? bK : bV)[rem];
#pragma unroll
        for (int r = 0; r < 4; r++) {
          const int grow = rowb + r;
          const int t = grow & 2047;
          float v = acc[mi][ni][r] + bb;
          float pv = __shfl_xor(v, 1);  // partner of the rope pair (adjacent col)
          if (qkv < 2) {
            const float c = cost[t * 32 + fi], s = sint[t * 32 + fi];
            float o = (d & 1) ? (pv * s + v * c) : (v * c - pv * s);
            if (qkv == 0) o *= 0.125f;  // fold 1/sqrt(64) into Q
            (qkv == 0 ? Qb : Kb)[(size_t)grow * 768 + rem] = f2bf(o);
          } else {
            const int bidx = grow >> 11;
            Vt[((size_t)(bidx * 12 + h) * 64 + d) * 2048 + t] = f2bf(v);
          }
        }
      } else {
        const float bb = bO[col];
#pragma unroll
        for (int r = 0; r < 4; r++) {
          const int grow = rowb + r;
          Out[(size_t)grow * 768 + col] = acc[mi][ni][r] + bb;
        }
      }
    }
  }
}

// ---------------- causal flash attention (paired q-tiles, balanced) ----------------
// grid (16, 24): block x processes q-tile (31-x) then q-tile x -> every block
// does exactly 33 kv-iterations (perfect static balance, 384 uniform blocks).
// 4 waves, each wave owns 16 q rows of the active tile.
// K/V staged in LDS via global_load_lds, double-buffered, one barrier per iter.
// Swizzle rule #21: linear LDS dest + pre-swizzled global source column +
// XOR-swizzled reads. P staging wave-private, swizzled.
// l-sum kept as per-lane partials; reduced across the 16 col-lanes once per tile.
__global__ __launch_bounds__(256) void attn_kernel(
    const u16* __restrict__ Qb, const u16* __restrict__ Kb,
    const u16* __restrict__ Vt, u16* __restrict__ Ob) {
  __shared__ char Kls[2][8192];   // [dbuf][64 key rows][128B]
  __shared__ char Vls[2][8192];   // [dbuf][64 d rows][128B]
  __shared__ char Pls[4][2048];   // per-wave [16 q][128B]
  const int bh = blockIdx.y;
  const int b = bh / 12, h = bh - b * 12;
  const int tid = threadIdx.x, w = tid >> 6, l = tid & 63;
  const int lr = l >> 4, lc = l & 15;

  const u16* kbase = Kb + (size_t)(b * 2048) * 768 + h * 64;
  const u16* vbase = Vt + (size_t)(bh * 64) * 2048;

  // staging source addressing (pre-swizzled column)
  const int srow = w * 8 + (l >> 3);        // tile-relative row (this wave's op0)
  const int scol8 = (l & 7) ^ (l >> 3);     // 16B granule within the 128B row
  const u16* ksrc0 = kbase + (size_t)srow * 768 + scol8 * 8;
  const u16* ksrc1 = kbase + (size_t)(srow + 32) * 768 + scol8 * 8;
  const u16* vsrc0 = vbase + (size_t)srow * 2048 + scol8 * 8;
  const u16* vsrc1 = vbase + (size_t)(srow + 32) * 2048 + scol8 * 8;

#define STAGE(t, bi)                                                   \
  {                                                                    \
    const size_t ko = (size_t)(t) * 64 * 768;                          \
    const int vo = (t) * 64;                                           \
    GLOAD16(ksrc0 + ko, &Kls[bi][w * 1024]);                           \
    GLOAD16(ksrc1 + ko, &Kls[bi][4096 + w * 1024]);                    \
    GLOAD16(vsrc0 + vo, &Vls[bi][w * 1024]);                           \
    GLOAD16(vsrc1 + vo, &Vls[bi][4096 + w * 1024]);                    \
  }

  char* pw = Pls[w];
  const int swz = (lc & 7) << 4;

#pragma unroll 1
  for (int half = 0; half < 2; half++) {
    const int qblk = half == 0 ? 31 - blockIdx.x : blockIdx.x;
    const int qw = qblk * 64 + w * 16;

    // Q fragments (A-operand): row = lc, k(d) = chunk*32 + lr*8
    const u16* qp = Qb + ((size_t)(b * 2048 + qw + lc)) * 768 + h * 64 + lr * 8;
    bf16x8 aq0 = *(const bf16x8*)qp;
    bf16x8 aq1 = *(const bf16x8*)(qp + 32);

    float m_run[4], l_run[4];
    f32x4 acc[4];
#pragma unroll
    for (int r = 0; r < 4; r++) { m_run[r] = -INFINITY; l_run[r] = 0.f; }
#pragma unroll
    for (int dt = 0; dt < 4; dt++) acc[dt] = (f32x4){0.f, 0.f, 0.f, 0.f};

    if (half == 1) __syncthreads();  // all waves done reading previous half's tiles
    STAGE(0, 0);
    __syncthreads();

    for (int kv = 0; kv <= qblk; kv++) {
      const int kv0 = kv * 64;
      const int cur = kv & 1;
      if (kv < qblk) STAGE(kv + 1, cur ^ 1);

      // S = Q K^T from LDS K tile
      f32x4 s[4];
#pragma unroll
      for (int kt = 0; kt < 4; kt++) {
        const char* kb_ = &Kls[cur][(kt * 16 + lc) * 128];
        bf16x8 bk0 = *(const bf16x8*)(kb_ + ((lr * 16) ^ swz));
        bf16x8 bk1 = *(const bf16x8*)(kb_ + ((64 + lr * 16) ^ swz));
        f32x4 sv = (f32x4){0.f, 0.f, 0.f, 0.f};
        sv = MFMA(aq0, bk0, sv);
        sv = MFMA(aq1, bk1, sv);
        s[kt] = sv;
      }

      if (kv == qblk) {  // causal mask inside diagonal tile
#pragma unroll
        for (int kt = 0; kt < 4; kt++)
#pragma unroll
          for (int r = 0; r < 4; r++)
            s[kt][r] = (kv0 + kt * 16 + lc > qw + lr * 4 + r) ? -INFINITY : s[kt][r];
      }

      float pm[4];
#pragma unroll
      for (int r = 0; r < 4; r++)
        pm[r] = fmaxf(fmaxf(s[0][r], s[1][r]), fmaxf(s[2][r], s[3][r]));
#pragma unroll
      for (int st = 1; st < 16; st <<= 1)
#pragma unroll
        for (int r = 0; r < 4; r++) pm[r] = fmaxf(pm[r], __shfl_xor(pm[r], st));

      float alpha[4], rs[4];
#pragma unroll
      for (int r = 0; r < 4; r++) {
        float mn = fmaxf(m_run[r], pm[r]);
        alpha[r] = __expf(m_run[r] - mn);
        m_run[r] = mn;
        rs[r] = 0.f;
      }

      // P = exp(S - m) -> swizzled per-wave LDS (bf16); rs stays per-lane partial
#pragma unroll
      for (int kt = 0; kt < 4; kt++)
#pragma unroll
        for (int r = 0; r < 4; r++) {
          float p = __expf(s[kt][r] - m_run[r]);
          rs[r] += p;
          const int q = lr * 4 + r;
          *(u16*)(pw + q * 128 + (((kt * 16 + lc) * 2) ^ ((q & 7) << 4))) = f2bf(p);
        }
#pragma unroll
      for (int r = 0; r < 4; r++) l_run[r] = l_run[r] * alpha[r] + rs[r];
#pragma unroll
      for (int dt = 0; dt < 4; dt++) {
        acc[dt][0] *= alpha[0]; acc[dt][1] *= alpha[1];
        acc[dt][2] *= alpha[2]; acc[dt][3] *= alpha[3];
      }

      // drain P ds_writes (intra-wave), then read P fragments
      asm volatile("s_waitcnt lgkmcnt(0)" ::: "memory");
      bf16x8 pa0 = *(const bf16x8*)(pw + lc * 128 + ((lr * 16) ^ swz));
      bf16x8 pa1 = *(const bf16x8*)(pw + lc * 128 + ((64 + lr * 16) ^ swz));
#pragma unroll
      for (int dt = 0; dt < 4; dt++) {
        const char* vb_ = &Vls[cur][(dt * 16 + lc) * 128];
        bf16x8 bv0 = *(const bf16x8*)(vb_ + ((lr * 16) ^ swz));
        bf16x8 bv1 = *(const bf16x8*)(vb_ + ((64 + lr * 16) ^ swz));
        acc[dt] = MFMA(pa0, bv0, acc[dt]);
        acc[dt] = MFMA(pa1, bv1, acc[dt]);
      }

      if (kv < qblk) __syncthreads();  // next tile staged + everyone done with cur
    }

    // reduce l across the 16 column-lanes (once per tile), then write O
#pragma unroll
    for (int st = 1; st < 16; st <<= 1)
#pragma unroll
      for (int r = 0; r < 4; r++) l_run[r] += __shfl_xor(l_run[r], st);
    float inv[4];
#pragma unroll
    for (int r = 0; r < 4; r++) inv[r] = 1.0f / l_run[r];
#pragma unroll
    for (int dt = 0; dt < 4; dt++)
#pragma unroll
      for (int r = 0; r < 4; r++) {
        const int q = qw + lr * 4 + r;
        Ob[((size_t)(b * 2048 + q)) * 768 + h * 64 + dt * 16 + lc] =
            f2bf(acc[dt][r] * inv[r]);
      }
  }
#undef STAGE
}

// ---------------- launcher ----------------

extern "C" void kernel_launch(void* const* d_in, const int* in_sizes, int n_in,
                              void* d_out, int out_size, void* d_ws, size_t ws_size,
                              hipStream_t stream) {
  const float* x  = (const float*)d_in[0];
  const float* WQ = (const float*)d_in[1];
  const float* bQ = (const float*)d_in[2];
  const float* WK = (const float*)d_in[3];
  const float* bK = (const float*)d_in[4];
  const float* WV = (const float*)d_in[5];
  const float* bV = (const float*)d_in[6];
  const float* WO = (const float*)d_in[7];
  const float* bO = (const float*)d_in[8];

  char* ws = (char*)d_ws;
  u16* Xb    = (u16*)(ws + 0);          // 4096x768 bf16
  u16* Wqkv  = (u16*)(ws + 6291456);    // 2304x768 bf16 (B^T)
  u16* WoT   = (u16*)(ws + 9830400);    // 768x768 bf16 (B^T)
  u16* Qb    = (u16*)(ws + 11010048);   // [B][T][768] bf16
  u16* Kb    = (u16*)(ws + 17301504);   // [B][T][768] bf16
  u16* Vt    = (u16*)(ws + 23592960);   // [bh][64][2048] bf16
  u16* Ob    = (u16*)(ws + 29884416);   // [B*T][768] bf16
  float* cost = (float*)(ws + 36175872); // [2048][32]
  float* sint = (float*)(ws + 36438016); // [2048][32]

  rope_tables<<<256, 256, 0, stream>>>(cost, sint);
  cast_x<<<3072, 256, 0, stream>>>(x, Xb, 4096 * 768);
  prep_wqkv<<<dim3(24, 2, 36), dim3(32, 8), 0, stream>>>(WQ, WK, WV, Wqkv);
  prep_wo<<<dim3(24, 24), dim3(32, 8), 0, stream>>>(WO, WoT);

  gemm_bt<0><<<dim3(32, 18), 256, 0, stream>>>(Xb, Wqkv, 768, 768, 768,
                                               bQ, bK, bV, cost, sint,
                                               Qb, Kb, Vt, nullptr, nullptr);
  attn_kernel<<<dim3(16, 24), 256, 0, stream>>>(Qb, Kb, Vt, Ob);
  gemm_bt<1><<<dim3(32, 6), 256, 0, stream>>>(Ob, WoT, 768, 768, 768,
                                              nullptr, nullptr, nullptr, nullptr, nullptr,
                                              nullptr, nullptr, nullptr, bO, (float*)d_out);
}

// Round 5
// 136.901 us; speedup vs baseline: 1.8710x; 1.0331x over previous
//
#include <hip/hip_runtime.h>

typedef unsigned short u16;
typedef short bf16x8 __attribute__((ext_vector_type(8)));
typedef float f32x4 __attribute__((ext_vector_type(4)));

#define MFMA(a, b, c) __builtin_amdgcn_mfma_f32_16x16x32_bf16(a, b, c, 0, 0, 0)

// f32 -> bf16 round-to-nearest-even
__device__ __forceinline__ u16 f2bf(float f) {
  unsigned int u = __float_as_uint(f);
  u = (u + 0x7FFFu + ((u >> 16) & 1u)) >> 16;
  return (u16)u;
}

// async global->LDS, 16B per lane; lds dest must be wave-uniform base (HW adds lane*16)
#define GLOAD16(gp, lp)                                                        \
  __builtin_amdgcn_global_load_lds(                                            \
      (const __attribute__((address_space(1))) void*)(gp),                     \
      (__attribute__((address_space(3))) void*)(lp), 16, 0, 0)

// ---------------- prep kernels ----------------

__global__ void rope_tables(float* __restrict__ cost, float* __restrict__ sint) {
  int idx = blockIdx.x * 256 + threadIdx.x;
  if (idx >= 2048 * 32) return;
  int t = idx >> 5, i = idx & 31;
  float invf = expf(-(float)i * 0.28782313662425572f);
  float ang = (float)t * invf;
  cost[idx] = cosf(ang);
  sint[idx] = sinf(ang);
}

__global__ void cast_x(const float* __restrict__ x, u16* __restrict__ xb, int n) {
  int i = (blockIdx.x * 256 + threadIdx.x) * 4;
  if (i >= n) return;
  float4 v = *(const float4*)(x + i);
  u16 o0 = f2bf(v.x), o1 = f2bf(v.y), o2 = f2bf(v.z), o3 = f2bf(v.w);
  ushort4 o = make_ushort4(o0, o1, o2, o3);
  *(ushort4*)(xb + i) = o;
}

// Wqkv_t[qkv*768 + h*64 + d][c] = W_{qkv}[h][c][d]   (bf16, B^T layout for GEMM)
__global__ void prep_wqkv(const float* __restrict__ WQ, const float* __restrict__ WK,
                          const float* __restrict__ WV, u16* __restrict__ Wt) {
  __shared__ float tile[32][33];
  const int z = blockIdx.z;              // 0..35
  const int qkv = z / 12, h = z - qkv * 12;
  const float* W = (qkv == 0 ? WQ : qkv == 1 ? WK : WV) + (size_t)h * 768 * 64;
  const int k0 = blockIdx.x * 32, d0 = blockIdx.y * 32;
  const int tx = threadIdx.x, ty = threadIdx.y;
#pragma unroll
  for (int it = 0; it < 4; it++)
    tile[ty + it * 8][tx] = W[(size_t)(k0 + ty + it * 8) * 64 + d0 + tx];
  __syncthreads();
  u16* out = Wt + (size_t)(qkv * 768 + h * 64 + d0) * 768 + k0;
#pragma unroll
  for (int it = 0; it < 4; it++)
    out[(size_t)(ty + it * 8) * 768 + tx] = f2bf(tile[tx][ty + it * 8]);
}

// WoT[m][hd] = W_O[hd][m]  (768x768 transpose, bf16)
__global__ void prep_wo(const float* __restrict__ WO, u16* __restrict__ Wt) {
  __shared__ float tile[32][33];
  const int a0 = blockIdx.x * 32, m0 = blockIdx.y * 32;
  const int tx = threadIdx.x, ty = threadIdx.y;
#pragma unroll
  for (int it = 0; it < 4; it++)
    tile[ty + it * 8][tx] = WO[(size_t)(a0 + ty + it * 8) * 768 + m0 + tx];
  __syncthreads();
#pragma unroll
  for (int it = 0; it < 4; it++)
    Wt[(size_t)(m0 + ty + it * 8) * 768 + a0 + tx] = f2bf(tile[tx][ty + it * 8]);
}

// ---------------- GEMM (128x128 tile, BK=32, 4 waves, 16x16x32 bf16 MFMA) ----------------
template <int MODE>
__global__ __launch_bounds__(256) void gemm_bt(
    const u16* __restrict__ A, const u16* __restrict__ Bt, int K, int LDA, int LDB,
    const float* __restrict__ bQ, const float* __restrict__ bK, const float* __restrict__ bV,
    const float* __restrict__ cost, const float* __restrict__ sint,
    u16* __restrict__ Qb, u16* __restrict__ Kb, u16* __restrict__ Vt,
    const float* __restrict__ bO, float* __restrict__ Out) {
  __shared__ u16 As[128 * 32];
  __shared__ u16 Bs[128 * 32];
  const int tid = threadIdx.x;
  const int w = tid >> 6, l = tid & 63;
  const int lr = l >> 4, lc = l & 15;
  const int wr = w >> 1, wc = w & 1;
  const int m0 = blockIdx.x * 128, n0 = blockIdx.y * 128;

  f32x4 acc[4][4];
#pragma unroll
  for (int mi = 0; mi < 4; mi++)
#pragma unroll
    for (int ni = 0; ni < 4; ni++) acc[mi][ni] = (f32x4){0.f, 0.f, 0.f, 0.f};

  for (int kt = 0; kt < K; kt += 32) {
    const u16* ga = A + (size_t)(m0 + w * 16 + (l >> 2)) * LDA + kt + (l & 3) * 8;
    const u16* gb = Bt + (size_t)(n0 + w * 16 + (l >> 2)) * LDB + kt + (l & 3) * 8;
    GLOAD16(ga, &As[w * 512]);
    GLOAD16(ga + (size_t)64 * LDA, &As[2048 + w * 512]);
    GLOAD16(gb, &Bs[w * 512]);
    GLOAD16(gb + (size_t)64 * LDB, &Bs[2048 + w * 512]);
    __syncthreads();

    bf16x8 af[4], bfr[4];
#pragma unroll
    for (int mi = 0; mi < 4; mi++)
      af[mi] = *(const bf16x8*)&As[(wr * 64 + mi * 16 + lc) * 32 + lr * 8];
#pragma unroll
    for (int ni = 0; ni < 4; ni++)
      bfr[ni] = *(const bf16x8*)&Bs[(wc * 64 + ni * 16 + lc) * 32 + lr * 8];
#pragma unroll
    for (int mi = 0; mi < 4; mi++)
#pragma unroll
      for (int ni = 0; ni < 4; ni++)
        acc[mi][ni] = MFMA(af[mi], bfr[ni], acc[mi][ni]);
    __syncthreads();
  }

#pragma unroll
  for (int mi = 0; mi < 4; mi++) {
#pragma unroll
    for (int ni = 0; ni < 4; ni++) {
      const int col = n0 + wc * 64 + ni * 16 + lc;
      const int rowb = m0 + wr * 64 + mi * 16 + lr * 4;
      if (MODE == 0) {
        const int qkv = col / 768;  // uniform per fragment (768 = 48*16)
        const int rem = col - qkv * 768;
        const int h = rem >> 6, d = rem & 63, fi = d >> 1;
        const float bb = (qkv == 0 ? bQ : qkv == 1 ? bK : bV)[rem];
#pragma unroll
        for (int r = 0; r < 4; r++) {
          const int grow = rowb + r;
          const int t = grow & 2047;
          float v = acc[mi][ni][r] + bb;
          float pv = __shfl_xor(v, 1);  // partner of the rope pair (adjacent col)
          if (qkv < 2) {
            const float c = cost[t * 32 + fi], s = sint[t * 32 + fi];
            float o = (d & 1) ? (pv * s + v * c) : (v * c - pv * s);
            if (qkv == 0) o *= 0.125f;  // fold 1/sqrt(64) into Q
            (qkv == 0 ? Qb : Kb)[(size_t)grow * 768 + rem] = f2bf(o);
          } else {
            const int bidx = grow >> 11;
            Vt[((size_t)(bidx * 12 + h) * 64 + d) * 2048 + t] = f2bf(v);
          }
        }
      } else {
        const float bb = bO[col];
#pragma unroll
        for (int r = 0; r < 4; r++) {
          const int grow = rowb + r;
          Out[(size_t)grow * 768 + col] = acc[mi][ni][r] + bb;
        }
      }
    }
  }
}

// ---------------- causal flash attention ----------------
// grid (16,24) flattened + XCD-swizzled: id=x+16y; xcd=id&7; bh=xcd+8*((id>>3)%3);
// xq=(id>>3)/3. All 16 xq-blocks of one bh land on ONE XCD -> its K/V slice
// (512KB) stays L2-resident (was 8x-duplicated across XCDs: 73MB HBM fetch).
// Block processes q-tiles (31-xq) then (xq): exactly 33 kv-iterations each.
// 3 LDS K/V buffers, prefetch depth 2, raw s_barrier + counted vmcnt(4) --
// in-flight loads never drain at the barrier (T3/T4).
__global__ __launch_bounds__(256) void attn_kernel(
    const u16* __restrict__ Qb, const u16* __restrict__ Kb,
    const u16* __restrict__ Vt, u16* __restrict__ Ob) {
  __shared__ char Kls[3][8192];   // [buf][64 key rows][128B]
  __shared__ char Vls[3][8192];   // [buf][64 d rows][128B]
  __shared__ char Pls[4][2048];   // per-wave [16 q][128B]
  const int id = blockIdx.x + 16 * blockIdx.y;
  const int s_ = id >> 3;
  const int bh = (id & 7) + 8 * (s_ % 3);  // same-bh blocks share an XCD
  const int xq = s_ / 3;                   // 0..15
  const int b = bh / 12, h = bh - b * 12;
  const int tid = threadIdx.x, w = tid >> 6, l = tid & 63;
  const int lr = l >> 4, lc = l & 15;

  const u16* kbase = Kb + (size_t)(b * 2048) * 768 + h * 64;
  const u16* vbase = Vt + (size_t)(bh * 64) * 2048;

  // staging source addressing (pre-swizzled column)
  const int srow = w * 8 + (l >> 3);        // tile-relative row (this wave's op0)
  const int scol8 = (l & 7) ^ (l >> 3);     // 16B granule within the 128B row
  const u16* ksrc0 = kbase + (size_t)srow * 768 + scol8 * 8;
  const u16* ksrc1 = kbase + (size_t)(srow + 32) * 768 + scol8 * 8;
  const u16* vsrc0 = vbase + (size_t)srow * 2048 + scol8 * 8;
  const u16* vsrc1 = vbase + (size_t)(srow + 32) * 2048 + scol8 * 8;

#define STAGE(t, bi)                                                   \
  {                                                                    \
    const size_t ko = (size_t)(t) * 64 * 768;                          \
    const int vo = (t) * 64;                                           \
    GLOAD16(ksrc0 + ko, &Kls[bi][w * 1024]);                           \
    GLOAD16(ksrc1 + ko, &Kls[bi][4096 + w * 1024]);                    \
    GLOAD16(vsrc0 + vo, &Vls[bi][w * 1024]);                           \
    GLOAD16(vsrc1 + vo, &Vls[bi][4096 + w * 1024]);                    \
  }

  char* pw = Pls[w];
  const int swz = (lc & 7) << 4;

#pragma unroll 1
  for (int half = 0; half < 2; half++) {
    const int qblk = half == 0 ? 31 - xq : xq;
    const int qw = qblk * 64 + w * 16;

    // Q fragments (A-operand): row = lc, k(d) = chunk*32 + lr*8
    const u16* qp = Qb + ((size_t)(b * 2048 + qw + lc)) * 768 + h * 64 + lr * 8;
    bf16x8 aq0 = *(const bf16x8*)qp;
    bf16x8 aq1 = *(const bf16x8*)(qp + 32);

    float m_run[4], l_run[4];
    f32x4 acc[4];
#pragma unroll
    for (int r = 0; r < 4; r++) { m_run[r] = -INFINITY; l_run[r] = 0.f; }
#pragma unroll
    for (int dt = 0; dt < 4; dt++) acc[dt] = (f32x4){0.f, 0.f, 0.f, 0.f};

    // all waves done reading previous half's buffers before restaging
    if (half == 1) __builtin_amdgcn_s_barrier();
    STAGE(0, 0);
    if (qblk > 0) STAGE(1, 1);

    for (int kv = 0; kv <= qblk; kv++) {
      const int kv0 = kv * 64;
      const int cur = kv % 3;

      // tile kv must be landed; tile kv+1 (4 loads) may stay in flight
      if (kv < qblk) asm volatile("s_waitcnt vmcnt(4)" ::: "memory");
      else           asm volatile("s_waitcnt vmcnt(0)" ::: "memory");
      __builtin_amdgcn_s_barrier();
      if (kv + 2 <= qblk) STAGE(kv + 2, (kv + 2) % 3);

      // S = Q K^T from LDS K tile
      f32x4 s[4];
#pragma unroll
      for (int kt = 0; kt < 4; kt++) {
        const char* kb_ = &Kls[cur][(kt * 16 + lc) * 128];
        bf16x8 bk0 = *(const bf16x8*)(kb_ + ((lr * 16) ^ swz));
        bf16x8 bk1 = *(const bf16x8*)(kb_ + ((64 + lr * 16) ^ swz));
        f32x4 sv = (f32x4){0.f, 0.f, 0.f, 0.f};
        sv = MFMA(aq0, bk0, sv);
        sv = MFMA(aq1, bk1, sv);
        s[kt] = sv;
      }

      if (kv == qblk) {  // causal mask inside diagonal tile
#pragma unroll
        for (int kt = 0; kt < 4; kt++)
#pragma unroll
          for (int r = 0; r < 4; r++)
            s[kt][r] = (kv0 + kt * 16 + lc > qw + lr * 4 + r) ? -INFINITY : s[kt][r];
      }

      float pm[4];
#pragma unroll
      for (int r = 0; r < 4; r++)
        pm[r] = fmaxf(fmaxf(s[0][r], s[1][r]), fmaxf(s[2][r], s[3][r]));
#pragma unroll
      for (int st = 1; st < 16; st <<= 1)
#pragma unroll
        for (int r = 0; r < 4; r++) pm[r] = fmaxf(pm[r], __shfl_xor(pm[r], st));

      float alpha[4], rs[4];
#pragma unroll
      for (int r = 0; r < 4; r++) {
        float mn = fmaxf(m_run[r], pm[r]);
        alpha[r] = __expf(m_run[r] - mn);
        m_run[r] = mn;
        rs[r] = 0.f;
      }

      // P = exp(S - m) -> swizzled per-wave LDS (bf16); rs stays per-lane partial
#pragma unroll
      for (int kt = 0; kt < 4; kt++)
#pragma unroll
        for (int r = 0; r < 4; r++) {
          float p = __expf(s[kt][r] - m_run[r]);
          rs[r] += p;
          const int q = lr * 4 + r;
          *(u16*)(pw + q * 128 + (((kt * 16 + lc) * 2) ^ ((q & 7) << 4))) = f2bf(p);
        }
#pragma unroll
      for (int r = 0; r < 4; r++) l_run[r] = l_run[r] * alpha[r] + rs[r];
#pragma unroll
      for (int dt = 0; dt < 4; dt++) {
        acc[dt][0] *= alpha[0]; acc[dt][1] *= alpha[1];
        acc[dt][2] *= alpha[2]; acc[dt][3] *= alpha[3];
      }

      // drain P ds_writes (intra-wave), then read P fragments
      asm volatile("s_waitcnt lgkmcnt(0)" ::: "memory");
      bf16x8 pa0 = *(const bf16x8*)(pw + lc * 128 + ((lr * 16) ^ swz));
      bf16x8 pa1 = *(const bf16x8*)(pw + lc * 128 + ((64 + lr * 16) ^ swz));
#pragma unroll
      for (int dt = 0; dt < 4; dt++) {
        const char* vb_ = &Vls[cur][(dt * 16 + lc) * 128];
        bf16x8 bv0 = *(const bf16x8*)(vb_ + ((lr * 16) ^ swz));
        bf16x8 bv1 = *(const bf16x8*)(vb_ + ((64 + lr * 16) ^ swz));
        acc[dt] = MFMA(pa0, bv0, acc[dt]);
        acc[dt] = MFMA(pa1, bv1, acc[dt]);
      }
      // no end-of-iteration barrier: next iteration's vmcnt+barrier fences
      // buffer reuse (buf (kv+2)%3 was last read in iteration kv-1)
    }

    // reduce l across the 16 column-lanes (once per tile), then write O
#pragma unroll
    for (int st = 1; st < 16; st <<= 1)
#pragma unroll
      for (int r = 0; r < 4; r++) l_run[r] += __shfl_xor(l_run[r], st);
    float inv[4];
#pragma unroll
    for (int r = 0; r < 4; r++) inv[r] = 1.0f / l_run[r];
#pragma unroll
    for (int dt = 0; dt < 4; dt++)
#pragma unroll
      for (int r = 0; r < 4; r++) {
        const int q = qw + lr * 4 + r;
        Ob[((size_t)(b * 2048 + q)) * 768 + h * 64 + dt * 16 + lc] =
            f2bf(acc[dt][r] * inv[r]);
      }
  }
#undef STAGE
}

// ---------------- launcher ----------------

extern "C" void kernel_launch(void* const* d_in, const int* in_sizes, int n_in,
                              void* d_out, int out_size, void* d_ws, size_t ws_size,
                              hipStream_t stream) {
  const float* x  = (const float*)d_in[0];
  const float* WQ = (const float*)d_in[1];
  const float* bQ = (const float*)d_in[2];
  const float* WK = (const float*)d_in[3];
  const float* bK = (const float*)d_in[4];
  const float* WV = (const float*)d_in[5];
  const float* bV = (const float*)d_in[6];
  const float* WO = (const float*)d_in[7];
  const float* bO = (const float*)d_in[8];

  char* ws = (char*)d_ws;
  u16* Xb    = (u16*)(ws + 0);          // 4096x768 bf16
  u16* Wqkv  = (u16*)(ws + 6291456);    // 2304x768 bf16 (B^T)
  u16* WoT   = (u16*)(ws + 9830400);    // 768x768 bf16 (B^T)
  u16* Qb    = (u16*)(ws + 11010048);   // [B][T][768] bf16
  u16* Kb    = (u16*)(ws + 17301504);   // [B][T][768] bf16
  u16* Vt    = (u16*)(ws + 23592960);   // [bh][64][2048] bf16
  u16* Ob    = (u16*)(ws + 29884416);   // [B*T][768] bf16
  float* cost = (float*)(ws + 36175872); // [2048][32]
  float* sint = (float*)(ws + 36438016); // [2048][32]

  rope_tables<<<256, 256, 0, stream>>>(cost, sint);
  cast_x<<<3072, 256, 0, stream>>>(x, Xb, 4096 * 768);
  prep_wqkv<<<dim3(24, 2, 36), dim3(32, 8), 0, stream>>>(WQ, WK, WV, Wqkv);
  prep_wo<<<dim3(24, 24), dim3(32, 8), 0, stream>>>(WO, WoT);

  gemm_bt<0><<<dim3(32, 18), 256, 0, stream>>>(Xb, Wqkv, 768, 768, 768,
                                               bQ, bK, bV, cost, sint,
                                               Qb, Kb, Vt, nullptr, nullptr);
  attn_kernel<<<dim3(16, 24), 256, 0, stream>>>(Qb, Kb, Vt, Ob);
  gemm_bt<1><<<dim3(32, 6), 256, 0, stream>>>(Ob, WoT, 768, 768, 768,
                                              nullptr, nullptr, nullptr, nullptr, nullptr,
                                              nullptr, nullptr, nullptr, bO, (float*)d_out);
}

// Round 6
// 135.645 us; speedup vs baseline: 1.8884x; 1.0093x over previous
//
#include <hip/hip_runtime.h>

typedef unsigned short u16;
typedef unsigned int u32;
typedef short bf16x8 __attribute__((ext_vector_type(8)));
typedef float f32x4 __attribute__((ext_vector_type(4)));
typedef float f32x16 __attribute__((ext_vector_type(16)));

#define MFMA(a, b, c) __builtin_amdgcn_mfma_f32_16x16x32_bf16(a, b, c, 0, 0, 0)
#define MFMA32(a, b, c) __builtin_amdgcn_mfma_f32_32x32x16_bf16(a, b, c, 0, 0, 0)

// f32 -> bf16 round-to-nearest-even
__device__ __forceinline__ u16 f2bf(float f) {
  unsigned int u = __float_as_uint(f);
  u = (u + 0x7FFFu + ((u >> 16) & 1u)) >> 16;
  return (u16)u;
}

// async global->LDS, 16B per lane; lds dest must be wave-uniform base (HW adds lane*16)
#define GLOAD16(gp, lp)                                                        \
  __builtin_amdgcn_global_load_lds(                                            \
      (const __attribute__((address_space(1))) void*)(gp),                     \
      (__attribute__((address_space(3))) void*)(lp), 16, 0, 0)

// ---------------- prep kernels ----------------

__global__ void rope_tables(float* __restrict__ cost, float* __restrict__ sint) {
  int idx = blockIdx.x * 256 + threadIdx.x;
  if (idx >= 2048 * 32) return;
  int t = idx >> 5, i = idx & 31;
  float invf = expf(-(float)i * 0.28782313662425572f);
  float ang = (float)t * invf;
  cost[idx] = cosf(ang);
  sint[idx] = sinf(ang);
}

__global__ void cast_x(const float* __restrict__ x, u16* __restrict__ xb, int n) {
  int i = (blockIdx.x * 256 + threadIdx.x) * 4;
  if (i >= n) return;
  float4 v = *(const float4*)(x + i);
  u16 o0 = f2bf(v.x), o1 = f2bf(v.y), o2 = f2bf(v.z), o3 = f2bf(v.w);
  ushort4 o = make_ushort4(o0, o1, o2, o3);
  *(ushort4*)(xb + i) = o;
}

// Wqkv_t[qkv*768 + h*64 + d][c] = W_{qkv}[h][c][d]   (bf16, B^T layout for GEMM)
__global__ void prep_wqkv(const float* __restrict__ WQ, const float* __restrict__ WK,
                          const float* __restrict__ WV, u16* __restrict__ Wt) {
  __shared__ float tile[32][33];
  const int z = blockIdx.z;              // 0..35
  const int qkv = z / 12, h = z - qkv * 12;
  const float* W = (qkv == 0 ? WQ : qkv == 1 ? WK : WV) + (size_t)h * 768 * 64;
  const int k0 = blockIdx.x * 32, d0 = blockIdx.y * 32;
  const int tx = threadIdx.x, ty = threadIdx.y;
#pragma unroll
  for (int it = 0; it < 4; it++)
    tile[ty + it * 8][tx] = W[(size_t)(k0 + ty + it * 8) * 64 + d0 + tx];
  __syncthreads();
  u16* out = Wt + (size_t)(qkv * 768 + h * 64 + d0) * 768 + k0;
#pragma unroll
  for (int it = 0; it < 4; it++)
    out[(size_t)(ty + it * 8) * 768 + tx] = f2bf(tile[tx][ty + it * 8]);
}

// WoT[m][hd] = W_O[hd][m]  (768x768 transpose, bf16)
__global__ void prep_wo(const float* __restrict__ WO, u16* __restrict__ Wt) {
  __shared__ float tile[32][33];
  const int a0 = blockIdx.x * 32, m0 = blockIdx.y * 32;
  const int tx = threadIdx.x, ty = threadIdx.y;
#pragma unroll
  for (int it = 0; it < 4; it++)
    tile[ty + it * 8][tx] = WO[(size_t)(a0 + ty + it * 8) * 768 + m0 + tx];
  __syncthreads();
#pragma unroll
  for (int it = 0; it < 4; it++)
    Wt[(size_t)(m0 + ty + it * 8) * 768 + a0 + tx] = f2bf(tile[tx][ty + it * 8]);
}

// ---------------- GEMM (128x128 tile, BK=32, 4 waves, 16x16x32 bf16 MFMA) ----------------
template <int MODE>
__global__ __launch_bounds__(256) void gemm_bt(
    const u16* __restrict__ A, const u16* __restrict__ Bt, int K, int LDA, int LDB,
    const float* __restrict__ bQ, const float* __restrict__ bK, const float* __restrict__ bV,
    const float* __restrict__ cost, const float* __restrict__ sint,
    u16* __restrict__ Qb, u16* __restrict__ Kb, u16* __restrict__ Vt,
    const float* __restrict__ bO, float* __restrict__ Out) {
  __shared__ u16 As[128 * 32];
  __shared__ u16 Bs[128 * 32];
  const int tid = threadIdx.x;
  const int w = tid >> 6, l = tid & 63;
  const int lr = l >> 4, lc = l & 15;
  const int wr = w >> 1, wc = w & 1;
  const int m0 = blockIdx.x * 128, n0 = blockIdx.y * 128;

  f32x4 acc[4][4];
#pragma unroll
  for (int mi = 0; mi < 4; mi++)
#pragma unroll
    for (int ni = 0; ni < 4; ni++) acc[mi][ni] = (f32x4){0.f, 0.f, 0.f, 0.f};

  for (int kt = 0; kt < K; kt += 32) {
    const u16* ga = A + (size_t)(m0 + w * 16 + (l >> 2)) * LDA + kt + (l & 3) * 8;
    const u16* gb = Bt + (size_t)(n0 + w * 16 + (l >> 2)) * LDB + kt + (l & 3) * 8;
    GLOAD16(ga, &As[w * 512]);
    GLOAD16(ga + (size_t)64 * LDA, &As[2048 + w * 512]);
    GLOAD16(gb, &Bs[w * 512]);
    GLOAD16(gb + (size_t)64 * LDB, &Bs[2048 + w * 512]);
    __syncthreads();

    bf16x8 af[4], bfr[4];
#pragma unroll
    for (int mi = 0; mi < 4; mi++)
      af[mi] = *(const bf16x8*)&As[(wr * 64 + mi * 16 + lc) * 32 + lr * 8];
#pragma unroll
    for (int ni = 0; ni < 4; ni++)
      bfr[ni] = *(const bf16x8*)&Bs[(wc * 64 + ni * 16 + lc) * 32 + lr * 8];
#pragma unroll
    for (int mi = 0; mi < 4; mi++)
#pragma unroll
      for (int ni = 0; ni < 4; ni++)
        acc[mi][ni] = MFMA(af[mi], bfr[ni], acc[mi][ni]);
    __syncthreads();
  }

#pragma unroll
  for (int mi = 0; mi < 4; mi++) {
#pragma unroll
    for (int ni = 0; ni < 4; ni++) {
      const int col = n0 + wc * 64 + ni * 16 + lc;
      const int rowb = m0 + wr * 64 + mi * 16 + lr * 4;
      if (MODE == 0) {
        const int qkv = col / 768;  // uniform per fragment (768 = 48*16)
        const int rem = col - qkv * 768;
        const int h = rem >> 6, d = rem & 63, fi = d >> 1;
        const float bb = (qkv == 0 ? bQ : qkv == 1 ? bK : bV)[rem];
#pragma unroll
        for (int r = 0; r < 4; r++) {
          const int grow = rowb + r;
          const int t = grow & 2047;
          float v = acc[mi][ni][r] + bb;
          float pv = __shfl_xor(v, 1);  // partner of the rope pair (adjacent col)
          if (qkv < 2) {
            const float c = cost[t * 32 + fi], s = sint[t * 32 + fi];
            float o = (d & 1) ? (pv * s + v * c) : (v * c - pv * s);
            if (qkv == 0) o *= 0.125f;  // fold 1/sqrt(64) into Q
            (qkv == 0 ? Qb : Kb)[(size_t)grow * 768 + rem] = f2bf(o);
          } else {
            const int bidx = grow >> 11;
            Vt[((size_t)(bidx * 12 + h) * 64 + d) * 2048 + t] = f2bf(v);
          }
        }
      } else {
        const float bb = bO[col];
#pragma unroll
        for (int r = 0; r < 4; r++) {
          const int grow = rowb + r;
          Out[(size_t)grow * 768 + col] = acc[mi][ni][r] + bb;
        }
      }
    }
  }
}

// ---------------- causal flash attention (32x32 swapped-QK^T, in-register P) ----------------
// 2 waves/block (128 thr), each wave owns 32 q rows; block = 64q tile-pair as before.
// S^T = mfma(A=K, B=Q): each lane owns ONE q row (col = l&31) -> softmax is in-lane
// (31 fmax + one shfl_xor(32)); P stays in registers: 16 cvt_pk + 8 permlane32_swap
// build the PV B-fragments. PV computes O^T = mfma(A=V^T, B=P^T); Vt is already V^T.
// K/V staged via global_load_lds, 3 buffers, counted vmcnt(8), 1 barrier/iter.
// LDS traffic per block-tile drops 96KB -> 48KB; no P LDS round-trip in the chain.
__global__ __launch_bounds__(128, 2) void attn_kernel(
    const u16* __restrict__ Qb, const u16* __restrict__ Kb,
    const u16* __restrict__ Vt, u16* __restrict__ Ob) {
  __shared__ char Kls[3][8192];   // [buf][64 key rows][128B d]
  __shared__ char Vls[3][8192];   // [buf][64 d rows][128B keys]
  const int id = blockIdx.x + 16 * blockIdx.y;
  const int s_ = id >> 3;
  const int bh = (id & 7) + 8 * (s_ % 3);  // same-bh blocks share an XCD
  const int xq = s_ / 3;                   // 0..15
  const int b = bh / 12, h = bh - b * 12;
  const int tid = threadIdx.x, w = tid >> 6, l = tid & 63;
  const int lq = l & 31, hi = l >> 5;

  const u16* kbase = Kb + (size_t)(b * 2048) * 768 + h * 64;
  const u16* vbase = Vt + (size_t)(bh * 64) * 2048;

  // staging: wave w covers tile rows w*32 + i*8 + (l>>3); pre-swizzled source col
  const int r8 = l >> 3;
  const int scol8 = (l & 7) ^ r8;
  const u16* ksrc = kbase + (size_t)(w * 32 + r8) * 768 + scol8 * 8;
  const u16* vsrc = vbase + (size_t)(w * 32 + r8) * 2048 + scol8 * 8;

#define STAGE(t, bi)                                                        \
  {                                                                         \
    const size_t ko = (size_t)(t) * 64 * 768;                               \
    const int vo = (t) * 64;                                                \
    GLOAD16(ksrc + ko,               &Kls[bi][w * 4096]);                   \
    GLOAD16(ksrc + ko + 8 * 768,     &Kls[bi][w * 4096 + 1024]);            \
    GLOAD16(ksrc + ko + 16 * 768,    &Kls[bi][w * 4096 + 2048]);            \
    GLOAD16(ksrc + ko + 24 * 768,    &Kls[bi][w * 4096 + 3072]);            \
    GLOAD16(vsrc + vo,               &Vls[bi][w * 4096]);                   \
    GLOAD16(vsrc + vo + 8 * 2048,    &Vls[bi][w * 4096 + 1024]);            \
    GLOAD16(vsrc + vo + 16 * 2048,   &Vls[bi][w * 4096 + 2048]);            \
    GLOAD16(vsrc + vo + 24 * 2048,   &Vls[bi][w * 4096 + 3072]);            \
  }

  const int fswz = (lq & 7) << 4;  // fragment-read XOR swizzle (row&7 pattern)

#pragma unroll 1
  for (int half = 0; half < 2; half++) {
    const int qblk = half == 0 ? 31 - xq : xq;

    // Q B-fragments: lane holds col=q=lq, k(d) = c*16 + hi*8 + j
    bf16x8 qf[4];
    {
      const u16* qp = Qb + ((size_t)(b * 2048 + qblk * 64 + w * 32 + lq)) * 768 + h * 64 + hi * 8;
#pragma unroll
      for (int c = 0; c < 4; c++) qf[c] = *(const bf16x8*)(qp + c * 16);
    }

    float m_run = -INFINITY, l_run = 0.f;
    f32x16 acc2[2];
    acc2[0] = (f32x16)0.0f;
    acc2[1] = (f32x16)0.0f;

    if (half == 1) __builtin_amdgcn_s_barrier();  // prev half's reads done
    STAGE(0, 0);
    if (qblk > 0) STAGE(1, 1);

    for (int kv = 0; kv <= qblk; kv++) {
      const int cur = kv % 3;
      if (kv < qblk) asm volatile("s_waitcnt vmcnt(8)" ::: "memory");
      else           asm volatile("s_waitcnt vmcnt(0)" ::: "memory");
      __builtin_amdgcn_s_barrier();
      __builtin_amdgcn_sched_barrier(0);
      if (kv + 2 <= qblk) STAGE(kv + 2, (kv + 2) % 3);

      // S^T[key][q] via mfma(A=K-frag, B=Q-frag); lane: q=lq, 16 keys per kt2 half
      f32x16 s2[2];
      s2[0] = (f32x16)0.0f;
      s2[1] = (f32x16)0.0f;
#pragma unroll
      for (int c = 0; c < 4; c++) {
        const int cb = (c * 32 + hi * 16) ^ fswz;
        bf16x8 kf0 = *(const bf16x8*)(&Kls[cur][lq * 128] + cb);
        bf16x8 kf1 = *(const bf16x8*)(&Kls[cur][(32 + lq) * 128] + cb);
        s2[0] = MFMA32(kf0, qf[c], s2[0]);
        s2[1] = MFMA32(kf1, qf[c], s2[1]);
      }

      if (kv == qblk) {  // causal mask: key offset (in-tile) > q offset (in-tile)
        const int qrel = w * 32 + lq;
#pragma unroll
        for (int kt2 = 0; kt2 < 2; kt2++)
#pragma unroll
          for (int r = 0; r < 16; r++) {
            const int ko = kt2 * 32 + (r & 3) + 8 * (r >> 2) + 4 * hi;
            if (ko > qrel) s2[kt2][r] = -INFINITY;
          }
      }

      // in-lane row max (one q per lane) + single cross-lane combine
      float pm = s2[0][0];
#pragma unroll
      for (int r = 1; r < 16; r++) pm = fmaxf(pm, s2[0][r]);
#pragma unroll
      for (int r = 0; r < 16; r++) pm = fmaxf(pm, s2[1][r]);
      pm = fmaxf(pm, __shfl_xor(pm, 32));

      const float mn = fmaxf(m_run, pm);
      const float alpha = __expf(m_run - mn);
      m_run = mn;

      // P = exp(S-m): pack pairs to bf16 in-register (keys 2j,2j+1 are regs 2j,2j+1)
      float rs = 0.f;
      u32 pk[2][8];
#pragma unroll
      for (int kt2 = 0; kt2 < 2; kt2++)
#pragma unroll
        for (int j = 0; j < 8; j++) {
          float p0 = __expf(s2[kt2][2 * j] - mn);
          float p1 = __expf(s2[kt2][2 * j + 1] - mn);
          rs += p0 + p1;
          asm("v_cvt_pk_bf16_f32 %0, %1, %2" : "=v"(pk[kt2][j]) : "v"(p0), "v"(p1));
        }
      l_run = l_run * alpha + rs;

      // P^T B-fragments via permlane32_swap: frag kq word t holds keys kq*16+hi*8+2t,+1
      union { u32 u[4]; bf16x8 v; } pf[4];
#pragma unroll
      for (int kq = 0; kq < 4; kq++) {
        const int kt2 = kq >> 1, i0 = 4 * (kq & 1);
        u32 a0 = pk[kt2][i0], b0 = pk[kt2][i0 + 2];
        u32 a1 = pk[kt2][i0 + 1], b1 = pk[kt2][i0 + 3];
        asm("v_permlane32_swap_b32 %0, %1" : "+v"(a0), "+v"(b0));
        asm("v_permlane32_swap_b32 %0, %1" : "+v"(a1), "+v"(b1));
        pf[kq].u[0] = a0; pf[kq].u[1] = a1; pf[kq].u[2] = b0; pf[kq].u[3] = b1;
      }

      // rescale O^T accumulator, then PV: acc2[dh] += mfma(V^T-frag, P^T-frag)
#pragma unroll
      for (int dh = 0; dh < 2; dh++)
#pragma unroll
        for (int r = 0; r < 16; r++) acc2[dh][r] *= alpha;

#pragma unroll
      for (int dh = 0; dh < 2; dh++) {
        const char* vr = &Vls[cur][(dh * 32 + lq) * 128];
#pragma unroll
        for (int kq = 0; kq < 4; kq++) {
          bf16x8 vf = *(const bf16x8*)(vr + ((kq * 32 + hi * 16) ^ fswz));
          acc2[dh] = MFMA32(vf, pf[kq].v, acc2[dh]);
        }
      }
    }

    // epilogue: combine l halves (lane pair l, l^32), write O (row q, packed d)
    const float lt = l_run + __shfl_xor(l_run, 32);
    const float inv = 1.0f / lt;
    u16* ob = Ob + ((size_t)(b * 2048 + qblk * 64 + w * 32 + lq)) * 768 + h * 64;
#pragma unroll
    for (int dh = 0; dh < 2; dh++)
#pragma unroll
      for (int g = 0; g < 4; g++) {
        ushort4 o4;
        o4.x = f2bf(acc2[dh][4 * g + 0] * inv);
        o4.y = f2bf(acc2[dh][4 * g + 1] * inv);
        o4.z = f2bf(acc2[dh][4 * g + 2] * inv);
        o4.w = f2bf(acc2[dh][4 * g + 3] * inv);
        *(ushort4*)(ob + dh * 32 + 8 * g + 4 * hi) = o4;
      }
  }
#undef STAGE
}

// ---------------- launcher ----------------

extern "C" void kernel_launch(void* const* d_in, const int* in_sizes, int n_in,
                              void* d_out, int out_size, void* d_ws, size_t ws_size,
                              hipStream_t stream) {
  const float* x  = (const float*)d_in[0];
  const float* WQ = (const float*)d_in[1];
  const float* bQ = (const float*)d_in[2];
  const float* WK = (const float*)d_in[3];
  const float* bK = (const float*)d_in[4];
  const float* WV = (const float*)d_in[5];
  const float* bV = (const float*)d_in[6];
  const float* WO = (const float*)d_in[7];
  const float* bO = (const float*)d_in[8];

  char* ws = (char*)d_ws;
  u16* Xb    = (u16*)(ws + 0);          // 4096x768 bf16
  u16* Wqkv  = (u16*)(ws + 6291456);    // 2304x768 bf16 (B^T)
  u16* WoT   = (u16*)(ws + 9830400);    // 768x768 bf16 (B^T)
  u16* Qb    = (u16*)(ws + 11010048);   // [B][T][768] bf16
  u16* Kb    = (u16*)(ws + 17301504);   // [B][T][768] bf16
  u16* Vt    = (u16*)(ws + 23592960);   // [bh][64][2048] bf16
  u16* Ob    = (u16*)(ws + 29884416);   // [B*T][768] bf16
  float* cost = (float*)(ws + 36175872); // [2048][32]
  float* sint = (float*)(ws + 36438016); // [2048][32]

  rope_tables<<<256, 256, 0, stream>>>(cost, sint);
  cast_x<<<3072, 256, 0, stream>>>(x, Xb, 4096 * 768);
  prep_wqkv<<<dim3(24, 2, 36), dim3(32, 8), 0, stream>>>(WQ, WK, WV, Wqkv);
  prep_wo<<<dim3(24, 24), dim3(32, 8), 0, stream>>>(WO, WoT);

  gemm_bt<0><<<dim3(32, 18), 256, 0, stream>>>(Xb, Wqkv, 768, 768, 768,
                                               bQ, bK, bV, cost, sint,
                                               Qb, Kb, Vt, nullptr, nullptr);
  attn_kernel<<<dim3(16, 24), 128, 0, stream>>>(Qb, Kb, Vt, Ob);
  gemm_bt<1><<<dim3(32, 6), 256, 0, stream>>>(Ob, WoT, 768, 768, 768,
                                              nullptr, nullptr, nullptr, nullptr, nullptr,
                                              nullptr, nullptr, nullptr, bO, (float*)d_out);
}

// Round 7
// 119.140 us; speedup vs baseline: 2.1500x; 1.1385x over previous
//
#include <hip/hip_runtime.h>

typedef unsigned short u16;
typedef unsigned int u32;
typedef short bf16x8 __attribute__((ext_vector_type(8)));
typedef float f32x4 __attribute__((ext_vector_type(4)));
typedef float f32x16 __attribute__((ext_vector_type(16)));

#define MFMA(a, b, c) __builtin_amdgcn_mfma_f32_16x16x32_bf16(a, b, c, 0, 0, 0)
#define MFMA32(a, b, c) __builtin_amdgcn_mfma_f32_32x32x16_bf16(a, b, c, 0, 0, 0)

// f32 -> bf16 round-to-nearest-even
__device__ __forceinline__ u16 f2bf(float f) {
  unsigned int u = __float_as_uint(f);
  u = (u + 0x7FFFu + ((u >> 16) & 1u)) >> 16;
  return (u16)u;
}

// async global->LDS, 16B per lane; lds dest must be wave-uniform base (HW adds lane*16)
#define GLOAD16(gp, lp)                                                        \
  __builtin_amdgcn_global_load_lds(                                            \
      (const __attribute__((address_space(1))) void*)(gp),                     \
      (__attribute__((address_space(3))) void*)(lp), 16, 0, 0)

// ---------------- prep kernels ----------------

__global__ void rope_tables(float* __restrict__ cost, float* __restrict__ sint) {
  int idx = blockIdx.x * 256 + threadIdx.x;
  if (idx >= 2048 * 32) return;
  int t = idx >> 5, i = idx & 31;
  float invf = expf(-(float)i * 0.28782313662425572f);
  float ang = (float)t * invf;
  cost[idx] = cosf(ang);
  sint[idx] = sinf(ang);
}

__global__ void cast_x(const float* __restrict__ x, u16* __restrict__ xb, int n) {
  int i = (blockIdx.x * 256 + threadIdx.x) * 4;
  if (i >= n) return;
  float4 v = *(const float4*)(x + i);
  u16 o0 = f2bf(v.x), o1 = f2bf(v.y), o2 = f2bf(v.z), o3 = f2bf(v.w);
  ushort4 o = make_ushort4(o0, o1, o2, o3);
  *(ushort4*)(xb + i) = o;
}

// Wqkv_t[qkv*768 + h*64 + d][c] = W_{qkv}[h][c][d]   (bf16, B^T layout for GEMM)
__global__ void prep_wqkv(const float* __restrict__ WQ, const float* __restrict__ WK,
                          const float* __restrict__ WV, u16* __restrict__ Wt) {
  __shared__ float tile[32][33];
  const int z = blockIdx.z;              // 0..35
  const int qkv = z / 12, h = z - qkv * 12;
  const float* W = (qkv == 0 ? WQ : qkv == 1 ? WK : WV) + (size_t)h * 768 * 64;
  const int k0 = blockIdx.x * 32, d0 = blockIdx.y * 32;
  const int tx = threadIdx.x, ty = threadIdx.y;
#pragma unroll
  for (int it = 0; it < 4; it++)
    tile[ty + it * 8][tx] = W[(size_t)(k0 + ty + it * 8) * 64 + d0 + tx];
  __syncthreads();
  u16* out = Wt + (size_t)(qkv * 768 + h * 64 + d0) * 768 + k0;
#pragma unroll
  for (int it = 0; it < 4; it++)
    out[(size_t)(ty + it * 8) * 768 + tx] = f2bf(tile[tx][ty + it * 8]);
}

// WoT[m][hd] = W_O[hd][m]  (768x768 transpose, bf16)
__global__ void prep_wo(const float* __restrict__ WO, u16* __restrict__ Wt) {
  __shared__ float tile[32][33];
  const int a0 = blockIdx.x * 32, m0 = blockIdx.y * 32;
  const int tx = threadIdx.x, ty = threadIdx.y;
#pragma unroll
  for (int it = 0; it < 4; it++)
    tile[ty + it * 8][tx] = WO[(size_t)(a0 + ty + it * 8) * 768 + m0 + tx];
  __syncthreads();
#pragma unroll
  for (int it = 0; it < 4; it++)
    Wt[(size_t)(m0 + ty + it * 8) * 768 + a0 + tx] = f2bf(tile[tx][ty + it * 8]);
}

// ---------------- GEMM (128x128 tile, BK=32, 4 waves, 16x16x32 bf16 MFMA) ----------------
template <int MODE>
__global__ __launch_bounds__(256) void gemm_bt(
    const u16* __restrict__ A, const u16* __restrict__ Bt, int K, int LDA, int LDB,
    const float* __restrict__ bQ, const float* __restrict__ bK, const float* __restrict__ bV,
    const float* __restrict__ cost, const float* __restrict__ sint,
    u16* __restrict__ Qb, u16* __restrict__ Kb, u16* __restrict__ Vt,
    const float* __restrict__ bO, float* __restrict__ Out) {
  __shared__ u16 As[128 * 32];
  __shared__ u16 Bs[128 * 32];
  const int tid = threadIdx.x;
  const int w = tid >> 6, l = tid & 63;
  const int lr = l >> 4, lc = l & 15;
  const int wr = w >> 1, wc = w & 1;
  const int m0 = blockIdx.x * 128, n0 = blockIdx.y * 128;

  f32x4 acc[4][4];
#pragma unroll
  for (int mi = 0; mi < 4; mi++)
#pragma unroll
    for (int ni = 0; ni < 4; ni++) acc[mi][ni] = (f32x4){0.f, 0.f, 0.f, 0.f};

  for (int kt = 0; kt < K; kt += 32) {
    const u16* ga = A + (size_t)(m0 + w * 16 + (l >> 2)) * LDA + kt + (l & 3) * 8;
    const u16* gb = Bt + (size_t)(n0 + w * 16 + (l >> 2)) * LDB + kt + (l & 3) * 8;
    GLOAD16(ga, &As[w * 512]);
    GLOAD16(ga + (size_t)64 * LDA, &As[2048 + w * 512]);
    GLOAD16(gb, &Bs[w * 512]);
    GLOAD16(gb + (size_t)64 * LDB, &Bs[2048 + w * 512]);
    __syncthreads();

    bf16x8 af[4], bfr[4];
#pragma unroll
    for (int mi = 0; mi < 4; mi++)
      af[mi] = *(const bf16x8*)&As[(wr * 64 + mi * 16 + lc) * 32 + lr * 8];
#pragma unroll
    for (int ni = 0; ni < 4; ni++)
      bfr[ni] = *(const bf16x8*)&Bs[(wc * 64 + ni * 16 + lc) * 32 + lr * 8];
#pragma unroll
    for (int mi = 0; mi < 4; mi++)
#pragma unroll
      for (int ni = 0; ni < 4; ni++)
        acc[mi][ni] = MFMA(af[mi], bfr[ni], acc[mi][ni]);
    __syncthreads();
  }

#pragma unroll
  for (int mi = 0; mi < 4; mi++) {
#pragma unroll
    for (int ni = 0; ni < 4; ni++) {
      const int col = n0 + wc * 64 + ni * 16 + lc;
      const int rowb = m0 + wr * 64 + mi * 16 + lr * 4;
      if (MODE == 0) {
        const int qkv = col / 768;  // uniform per fragment (768 = 48*16)
        const int rem = col - qkv * 768;
        const int h = rem >> 6, d = rem & 63, fi = d >> 1;
        const float bb = (qkv == 0 ? bQ : qkv == 1 ? bK : bV)[rem];
#pragma unroll
        for (int r = 0; r < 4; r++) {
          const int grow = rowb + r;
          const int t = grow & 2047;
          float v = acc[mi][ni][r] + bb;
          float pv = __shfl_xor(v, 1);  // partner of the rope pair (adjacent col)
          if (qkv < 2) {
            const float c = cost[t * 32 + fi], s = sint[t * 32 + fi];
            float o = (d & 1) ? (pv * s + v * c) : (v * c - pv * s);
            if (qkv == 0) o *= 0.125f;  // fold 1/sqrt(64) into Q
            (qkv == 0 ? Qb : Kb)[(size_t)grow * 768 + rem] = f2bf(o);
          } else {
            const int bidx = grow >> 11;
            Vt[((size_t)(bidx * 12 + h) * 64 + d) * 2048 + t] = f2bf(v);
          }
        }
      } else {
        const float bb = bO[col];
#pragma unroll
        for (int r = 0; r < 4; r++) {
          const int grow = rowb + r;
          Out[(size_t)grow * 768 + col] = acc[mi][ni][r] + bb;
        }
      }
    }
  }
}

// ---------------- causal flash attention ----------------
// 32x32 swapped-QK^T, in-register P (R6 structure) + kv-parity wave groups:
// 256 thr = 4 waves = 2 q-halves x 2 kv-groups. Group g handles kv tiles
// {g, g+2, ...}; each super-iteration consumes 2 tiles from a 4-buffer shared
// staging pipeline (each tile staged ONCE by all 4 waves). Groups merge their
// partial (m, l, accO) once per tile-phase via LDS scratch (reuses staging bufs).
// Pairing keeps every block at ~17 uniform super-iterations; 64KB LDS ->
// 2 blocks/CU = 8 waves/CU (4x R6's residency).
__global__ __launch_bounds__(256, 2) void attn_kernel(
    const u16* __restrict__ Qb, const u16* __restrict__ Kb,
    const u16* __restrict__ Vt, u16* __restrict__ Ob) {
  __shared__ char Kls[4][8192];   // [buf][64 key rows][128B d]
  __shared__ char Vls[4][8192];   // [buf][64 d rows][128B keys]
  char* scratch = (char*)Kls;     // merge scratch: 2*64*34*4 = 17408B (barrier-ordered reuse)

  const int id = blockIdx.x + 16 * blockIdx.y;
  const int s_ = id >> 3;
  const int bh = (id & 7) + 8 * (s_ % 3);  // same-bh blocks share an XCD
  const int xq = s_ / 3;                   // 0..15
  const int b = bh / 12, h = bh - b * 12;
  const int tid = threadIdx.x, w = tid >> 6, l = tid & 63;
  const int lq = l & 31, hi = l >> 5;
  const int qhalf = w & 1, grp = w >> 1;

  const u16* kbase = Kb + (size_t)(b * 2048) * 768 + h * 64;
  const u16* vbase = Vt + (size_t)(bh * 64) * 2048;

  // staging: wave w stages rows [16w, 16w+16) of both K and V; pre-swizzled col
  const int r8 = l >> 3;
  const int scol8 = (l & 7) ^ r8;
  const u16* ksrc = kbase + (size_t)(w * 16 + r8) * 768 + scol8 * 8;
  const u16* vsrc = vbase + (size_t)(w * 16 + r8) * 2048 + scol8 * 8;

#define STAGE(t, bi)                                                        \
  {                                                                         \
    const size_t ko = (size_t)(t) * 64 * 768;                               \
    const int vo = (t) * 64;                                                \
    GLOAD16(ksrc + ko,            &Kls[bi][w * 2048]);                      \
    GLOAD16(ksrc + ko + 8 * 768,  &Kls[bi][w * 2048 + 1024]);               \
    GLOAD16(vsrc + vo,            &Vls[bi][w * 2048]);                      \
    GLOAD16(vsrc + vo + 8 * 2048, &Vls[bi][w * 2048 + 1024]);               \
  }

  const int fswz = (lq & 7) << 4;  // fragment-read XOR swizzle

#pragma unroll 1
  for (int half = 0; half < 2; half++) {
    const int qblk = half == 0 ? 31 - xq : xq;
    const int n = qblk + 1;          // kv tiles this phase
    const int nsup = (n + 1) >> 1;   // super-iterations

    // Q B-fragments: lane holds col=q=(qhalf*32+lq), k(d) = c*16 + hi*8 + j
    bf16x8 qf[4];
    {
      const u16* qp = Qb + ((size_t)(b * 2048 + qblk * 64 + qhalf * 32 + lq)) * 768 +
                      h * 64 + hi * 8;
#pragma unroll
      for (int c = 0; c < 4; c++) qf[c] = *(const bf16x8*)(qp + c * 16);
    }

    float m_run = -INFINITY, l_run = 0.f;
    f32x16 acc2[2];
    acc2[0] = (f32x16)0.0f;
    acc2[1] = (f32x16)0.0f;

    // prologue: stage tiles 0 (and 1)
    STAGE(0, 0);
    if (n > 1) STAGE(1, 1);

    for (int p = 0; p < nsup; p++) {
      const int t0 = 2 * p;
      asm volatile("s_waitcnt vmcnt(0)" ::: "memory");  // tiles t0, t0+1 landed
      __builtin_amdgcn_s_barrier();
      __builtin_amdgcn_sched_barrier(0);
      if (t0 + 2 < n) STAGE(t0 + 2, (t0 + 2) & 3);
      if (t0 + 3 < n) STAGE(t0 + 3, (t0 + 3) & 3);

      const int tile = t0 + grp;
      if (tile < n) {
        const int cur = tile & 3;

        // S^T[key][q] via mfma(A=K-frag, B=Q-frag)
        f32x16 s2[2];
        s2[0] = (f32x16)0.0f;
        s2[1] = (f32x16)0.0f;
        __builtin_amdgcn_s_setprio(1);
#pragma unroll
        for (int c = 0; c < 4; c++) {
          const int cb = (c * 32 + hi * 16) ^ fswz;
          bf16x8 kf0 = *(const bf16x8*)(&Kls[cur][lq * 128] + cb);
          bf16x8 kf1 = *(const bf16x8*)(&Kls[cur][(32 + lq) * 128] + cb);
          s2[0] = MFMA32(kf0, qf[c], s2[0]);
          s2[1] = MFMA32(kf1, qf[c], s2[1]);
        }
        __builtin_amdgcn_s_setprio(0);

        if (tile == qblk) {  // causal mask inside diagonal tile
          const int qrel = qhalf * 32 + lq;
#pragma unroll
          for (int kt2 = 0; kt2 < 2; kt2++)
#pragma unroll
            for (int r = 0; r < 16; r++) {
              const int ko = kt2 * 32 + (r & 3) + 8 * (r >> 2) + 4 * hi;
              if (ko > qrel) s2[kt2][r] = -INFINITY;
            }
        }

        // in-lane row max (one q per lane) + single cross-lane combine
        float pm = s2[0][0];
#pragma unroll
        for (int r = 1; r < 16; r++) pm = fmaxf(pm, s2[0][r]);
#pragma unroll
        for (int r = 0; r < 16; r++) pm = fmaxf(pm, s2[1][r]);
        pm = fmaxf(pm, __shfl_xor(pm, 32));

        const float mn = fmaxf(m_run, pm);
        const float alpha = __expf(m_run - mn);
        m_run = mn;

        // P = exp(S-m): pack pairs to bf16 in-register
        float rs = 0.f;
        u32 pk[2][8];
#pragma unroll
        for (int kt2 = 0; kt2 < 2; kt2++)
#pragma unroll
          for (int j = 0; j < 8; j++) {
            float p0 = __expf(s2[kt2][2 * j] - mn);
            float p1 = __expf(s2[kt2][2 * j + 1] - mn);
            rs += p0 + p1;
            asm("v_cvt_pk_bf16_f32 %0, %1, %2" : "=v"(pk[kt2][j]) : "v"(p0), "v"(p1));
          }
        l_run = l_run * alpha + rs;

        // P^T B-fragments via permlane32_swap
        union { u32 u[4]; bf16x8 v; } pf[4];
#pragma unroll
        for (int kq = 0; kq < 4; kq++) {
          const int kt2 = kq >> 1, i0 = 4 * (kq & 1);
          u32 a0 = pk[kt2][i0], b0 = pk[kt2][i0 + 2];
          u32 a1 = pk[kt2][i0 + 1], b1 = pk[kt2][i0 + 3];
          asm("v_permlane32_swap_b32 %0, %1" : "+v"(a0), "+v"(b0));
          asm("v_permlane32_swap_b32 %0, %1" : "+v"(a1), "+v"(b1));
          pf[kq].u[0] = a0; pf[kq].u[1] = a1; pf[kq].u[2] = b0; pf[kq].u[3] = b1;
        }

        // rescale O^T accumulator, then PV
#pragma unroll
        for (int dh = 0; dh < 2; dh++)
#pragma unroll
          for (int r = 0; r < 16; r++) acc2[dh][r] *= alpha;

        __builtin_amdgcn_s_setprio(1);
#pragma unroll
        for (int dh = 0; dh < 2; dh++) {
          const char* vr = &Vls[cur][(dh * 32 + lq) * 128];
#pragma unroll
          for (int kq = 0; kq < 4; kq++) {
            bf16x8 vf = *(const bf16x8*)(vr + ((kq * 32 + hi * 16) ^ fswz));
            acc2[dh] = MFMA32(vf, pf[kq].v, acc2[dh]);
          }
        }
        __builtin_amdgcn_s_setprio(0);
      }
    }

    // ---- merge the two kv-groups via LDS scratch ----
    asm volatile("s_waitcnt lgkmcnt(0)" ::: "memory");
    __builtin_amdgcn_s_barrier();  // A: all compute (and LDS reads) done
    if (grp == 1) {
      float* sc = (float*)scratch + ((size_t)(w - 2) * 64 + l) * 34;
#pragma unroll
      for (int dh = 0; dh < 2; dh++)
#pragma unroll
        for (int r = 0; r < 16; r++) sc[dh * 16 + r] = acc2[dh][r];
      sc[32] = m_run;
      sc[33] = l_run;
    }
    asm volatile("s_waitcnt lgkmcnt(0)" ::: "memory");
    __builtin_amdgcn_s_barrier();  // B: group-1 state visible
    if (grp == 0) {
      const float* sc = (const float*)scratch + ((size_t)w * 64 + l) * 34;
      const float m1 = sc[32], l1 = sc[33];
      const float M = fmaxf(m_run, m1);
      const float a0 = __expf(m_run - M);
      const float a1 = __expf(m1 - M);   // exp(-inf - finite) = 0 when group1 idle
      const float lm = l_run * a0 + l1 * a1;
      const float lt = lm + __shfl_xor(lm, 32);
      const float inv = 1.0f / lt;
      u16* ob = Ob + ((size_t)(b * 2048 + qblk * 64 + qhalf * 32 + lq)) * 768 + h * 64;
#pragma unroll
      for (int dh = 0; dh < 2; dh++)
#pragma unroll
        for (int g = 0; g < 4; g++) {
          ushort4 o4;
          o4.x = f2bf((acc2[dh][4 * g + 0] * a0 + sc[dh * 16 + 4 * g + 0] * a1) * inv);
          o4.y = f2bf((acc2[dh][4 * g + 1] * a0 + sc[dh * 16 + 4 * g + 1] * a1) * inv);
          o4.z = f2bf((acc2[dh][4 * g + 2] * a0 + sc[dh * 16 + 4 * g + 2] * a1) * inv);
          o4.w = f2bf((acc2[dh][4 * g + 3] * a0 + sc[dh * 16 + 4 * g + 3] * a1) * inv);
          *(ushort4*)(ob + dh * 32 + 8 * g + 4 * hi) = o4;
        }
    }
    asm volatile("s_waitcnt lgkmcnt(0)" ::: "memory");
    __builtin_amdgcn_s_barrier();  // C: scratch reads done before next-phase staging
  }
#undef STAGE
}

// ---------------- launcher ----------------

extern "C" void kernel_launch(void* const* d_in, const int* in_sizes, int n_in,
                              void* d_out, int out_size, void* d_ws, size_t ws_size,
                              hipStream_t stream) {
  const float* x  = (const float*)d_in[0];
  const float* WQ = (const float*)d_in[1];
  const float* bQ = (const float*)d_in[2];
  const float* WK = (const float*)d_in[3];
  const float* bK = (const float*)d_in[4];
  const float* WV = (const float*)d_in[5];
  const float* bV = (const float*)d_in[6];
  const float* WO = (const float*)d_in[7];
  const float* bO = (const float*)d_in[8];

  char* ws = (char*)d_ws;
  u16* Xb    = (u16*)(ws + 0);          // 4096x768 bf16
  u16* Wqkv  = (u16*)(ws + 6291456);    // 2304x768 bf16 (B^T)
  u16* WoT   = (u16*)(ws + 9830400);    // 768x768 bf16 (B^T)
  u16* Qb    = (u16*)(ws + 11010048);   // [B][T][768] bf16
  u16* Kb    = (u16*)(ws + 17301504);   // [B][T][768] bf16
  u16* Vt    = (u16*)(ws + 23592960);   // [bh][64][2048] bf16
  u16* Ob    = (u16*)(ws + 29884416);   // [B*T][768] bf16
  float* cost = (float*)(ws + 36175872); // [2048][32]
  float* sint = (float*)(ws + 36438016); // [2048][32]

  rope_tables<<<256, 256, 0, stream>>>(cost, sint);
  cast_x<<<3072, 256, 0, stream>>>(x, Xb, 4096 * 768);
  prep_wqkv<<<dim3(24, 2, 36), dim3(32, 8), 0, stream>>>(WQ, WK, WV, Wqkv);
  prep_wo<<<dim3(24, 24), dim3(32, 8), 0, stream>>>(WO, WoT);

  gemm_bt<0><<<dim3(32, 18), 256, 0, stream>>>(Xb, Wqkv, 768, 768, 768,
                                               bQ, bK, bV, cost, sint,
                                               Qb, Kb, Vt, nullptr, nullptr);
  attn_kernel<<<dim3(16, 24), 256, 0, stream>>>(Qb, Kb, Vt, Ob);
  gemm_bt<1><<<dim3(32, 6), 256, 0, stream>>>(Ob, WoT, 768, 768, 768,
                                              nullptr, nullptr, nullptr, nullptr, nullptr,
                                              nullptr, nullptr, nullptr, bO, (float*)d_out);
}

// Round 8
// 115.775 us; speedup vs baseline: 2.2125x; 1.0291x over previous
//
#include <hip/hip_runtime.h>

typedef unsigned short u16;
typedef unsigned int u32;
typedef short bf16x8 __attribute__((ext_vector_type(8)));
typedef float f32x4 __attribute__((ext_vector_type(4)));
typedef float f32x16 __attribute__((ext_vector_type(16)));

#define MFMA(a, b, c) __builtin_amdgcn_mfma_f32_16x16x32_bf16(a, b, c, 0, 0, 0)
#define MFMA32(a, b, c) __builtin_amdgcn_mfma_f32_32x32x16_bf16(a, b, c, 0, 0, 0)

// f32 -> bf16 round-to-nearest-even
__device__ __forceinline__ u16 f2bf(float f) {
  unsigned int u = __float_as_uint(f);
  u = (u + 0x7FFFu + ((u >> 16) & 1u)) >> 16;
  return (u16)u;
}

// async global->LDS, 16B per lane; lds dest must be wave-uniform base (HW adds lane*16)
#define GLOAD16(gp, lp)                                                        \
  __builtin_amdgcn_global_load_lds(                                            \
      (const __attribute__((address_space(1))) void*)(gp),                     \
      (__attribute__((address_space(3))) void*)(lp), 16, 0, 0)

// ---------------- prep kernels ----------------

__global__ void rope_tables(float* __restrict__ cost, float* __restrict__ sint) {
  int idx = blockIdx.x * 256 + threadIdx.x;
  if (idx >= 2048 * 32) return;
  int t = idx >> 5, i = idx & 31;
  float invf = expf(-(float)i * 0.28782313662425572f);
  float ang = (float)t * invf;
  cost[idx] = cosf(ang);
  sint[idx] = sinf(ang);
}

__global__ void cast_x(const float* __restrict__ x, u16* __restrict__ xb, int n) {
  int i = (blockIdx.x * 256 + threadIdx.x) * 4;
  if (i >= n) return;
  float4 v = *(const float4*)(x + i);
  u16 o0 = f2bf(v.x), o1 = f2bf(v.y), o2 = f2bf(v.z), o3 = f2bf(v.w);
  ushort4 o = make_ushort4(o0, o1, o2, o3);
  *(ushort4*)(xb + i) = o;
}

// Wqkv_t[qkv*768 + h*64 + d][c] = W_{qkv}[h][c][d]   (bf16, B^T layout for GEMM)
__global__ void prep_wqkv(const float* __restrict__ WQ, const float* __restrict__ WK,
                          const float* __restrict__ WV, u16* __restrict__ Wt) {
  __shared__ float tile[32][33];
  const int z = blockIdx.z;              // 0..35
  const int qkv = z / 12, h = z - qkv * 12;
  const float* W = (qkv == 0 ? WQ : qkv == 1 ? WK : WV) + (size_t)h * 768 * 64;
  const int k0 = blockIdx.x * 32, d0 = blockIdx.y * 32;
  const int tx = threadIdx.x, ty = threadIdx.y;
#pragma unroll
  for (int it = 0; it < 4; it++)
    tile[ty + it * 8][tx] = W[(size_t)(k0 + ty + it * 8) * 64 + d0 + tx];
  __syncthreads();
  u16* out = Wt + (size_t)(qkv * 768 + h * 64 + d0) * 768 + k0;
#pragma unroll
  for (int it = 0; it < 4; it++)
    out[(size_t)(ty + it * 8) * 768 + tx] = f2bf(tile[tx][ty + it * 8]);
}

// WoT[m][hd] = W_O[hd][m]  (768x768 transpose, bf16)
__global__ void prep_wo(const float* __restrict__ WO, u16* __restrict__ Wt) {
  __shared__ float tile[32][33];
  const int a0 = blockIdx.x * 32, m0 = blockIdx.y * 32;
  const int tx = threadIdx.x, ty = threadIdx.y;
#pragma unroll
  for (int it = 0; it < 4; it++)
    tile[ty + it * 8][tx] = WO[(size_t)(a0 + ty + it * 8) * 768 + m0 + tx];
  __syncthreads();
#pragma unroll
  for (int it = 0; it < 4; it++)
    Wt[(size_t)(m0 + ty + it * 8) * 768 + a0 + tx] = f2bf(tile[tx][ty + it * 8]);
}

// ---------------- GEMM (128x128 tile, BK=32, deep-pipelined) ----------------
// 3 LDS buffers, prefetch depth 2, ONE raw s_barrier/iter + counted vmcnt(4)
// (never drains in the main loop -- the m97 barrier-drain is the known ~4x cost
// at this problem size). LDS swizzle rule #21: linear gload_lds dest +
// pre-swizzled source granule ((l&3)^((l>>3)&3)) + read granule lr^((row>>1)&3)
// -> 8-way conflict becomes free 2-way. XCD m-chunking: each XCD owns 4
// m-blocks x all n -> A-slice (0.8MB) + B-panel stay L2-resident.
template <int MODE>
__global__ __launch_bounds__(256) void gemm_bt(
    const u16* __restrict__ A, const u16* __restrict__ Bt, int K, int LDA, int LDB,
    const float* __restrict__ bQ, const float* __restrict__ bK, const float* __restrict__ bV,
    const float* __restrict__ cost, const float* __restrict__ sint,
    u16* __restrict__ Qb, u16* __restrict__ Kb, u16* __restrict__ Vt,
    const float* __restrict__ bO, float* __restrict__ Out) {
  __shared__ u16 As[3][128 * 32];
  __shared__ u16 Bs[3][128 * 32];
  const int tid = threadIdx.x;
  const int w = tid >> 6, l = tid & 63;
  const int lr = l >> 4, lc = l & 15;
  const int wr = w >> 1, wc = w & 1;

  // XCD-aware block remap (gridDim.x == 32 == 8 XCD-chunks of 4 m-blocks)
  const int id = blockIdx.x + (int)gridDim.x * blockIdx.y;
  const int xcd = id & 7, idx = id >> 3;
  const int m0 = (xcd * 4 + (idx & 3)) * 128;
  const int n0 = (idx >> 2) * 128;

  f32x4 acc[4][4];
#pragma unroll
  for (int mi = 0; mi < 4; mi++)
#pragma unroll
    for (int ni = 0; ni < 4; ni++) acc[mi][ni] = (f32x4){0.f, 0.f, 0.f, 0.f};

  // staging: lane stages row w*16+(l>>2) (and +64), src granule (l&3)^((l>>3)&3)
  const int srow = w * 16 + (l >> 2);
  const int sg = (l & 3) ^ ((l >> 3) & 3);
  const u16* ga = A + (size_t)(m0 + srow) * LDA + sg * 8;
  const u16* gb = Bt + (size_t)(n0 + srow) * LDB + sg * 8;

#define GSTAGE(t, bi)                                                   \
  {                                                                     \
    const int kk = (t) * 32;                                            \
    GLOAD16(ga + kk, &As[bi][w * 512]);                                 \
    GLOAD16(ga + kk + (size_t)64 * LDA, &As[bi][2048 + w * 512]);       \
    GLOAD16(gb + kk, &Bs[bi][w * 512]);                                 \
    GLOAD16(gb + kk + (size_t)64 * LDB, &Bs[bi][2048 + w * 512]);       \
  }

  const int n = K >> 5;
  GSTAGE(0, 0);
  if (n > 1) GSTAGE(1, 1);

  for (int kt = 0; kt < n; kt++) {
    if (kt + 1 < n) asm volatile("s_waitcnt vmcnt(4)" ::: "memory");
    else            asm volatile("s_waitcnt vmcnt(0)" ::: "memory");
    __builtin_amdgcn_s_barrier();
    __builtin_amdgcn_sched_barrier(0);
    if (kt + 2 < n) GSTAGE(kt + 2, (kt + 2) % 3);

    const char* as = (const char*)As[kt % 3];
    const char* bs = (const char*)Bs[kt % 3];
    bf16x8 af[4], bfr[4];
#pragma unroll
    for (int mi = 0; mi < 4; mi++) {
      const int row = wr * 64 + mi * 16 + lc;
      af[mi] = *(const bf16x8*)(as + row * 64 + ((lr ^ ((row >> 1) & 3)) << 4));
    }
#pragma unroll
    for (int ni = 0; ni < 4; ni++) {
      const int row = wc * 64 + ni * 16 + lc;
      bfr[ni] = *(const bf16x8*)(bs + row * 64 + ((lr ^ ((row >> 1) & 3)) << 4));
    }
    __builtin_amdgcn_s_setprio(1);
#pragma unroll
    for (int mi = 0; mi < 4; mi++)
#pragma unroll
      for (int ni = 0; ni < 4; ni++)
        acc[mi][ni] = MFMA(af[mi], bfr[ni], acc[mi][ni]);
    __builtin_amdgcn_s_setprio(0);
    // no trailing barrier: next iteration's vmcnt+barrier fences buffer reuse
  }
#undef GSTAGE

#pragma unroll
  for (int mi = 0; mi < 4; mi++) {
#pragma unroll
    for (int ni = 0; ni < 4; ni++) {
      const int col = n0 + wc * 64 + ni * 16 + lc;
      const int rowb = m0 + wr * 64 + mi * 16 + lr * 4;
      if (MODE == 0) {
        const int qkv = col / 768;  // uniform per fragment (768 = 48*16)
        const int rem = col - qkv * 768;
        const int h = rem >> 6, d = rem & 63, fi = d >> 1;
        const float bb = (qkv == 0 ? bQ : qkv == 1 ? bK : bV)[rem];
#pragma unroll
        for (int r = 0; r < 4; r++) {
          const int grow = rowb + r;
          const int t = grow & 2047;
          float v = acc[mi][ni][r] + bb;
          float pv = __shfl_xor(v, 1);  // partner of the rope pair (adjacent col)
          if (qkv < 2) {
            const float c = cost[t * 32 + fi], s = sint[t * 32 + fi];
            float o = (d & 1) ? (pv * s + v * c) : (v * c - pv * s);
            if (qkv == 0) o *= 0.125f;  // fold 1/sqrt(64) into Q
            (qkv == 0 ? Qb : Kb)[(size_t)grow * 768 + rem] = f2bf(o);
          } else {
            const int bidx = grow >> 11;
            Vt[((size_t)(bidx * 12 + h) * 64 + d) * 2048 + t] = f2bf(v);
          }
        }
      } else {
        const float bb = bO[col];
#pragma unroll
        for (int r = 0; r < 4; r++) {
          const int grow = rowb + r;
          Out[(size_t)grow * 768 + col] = acc[mi][ni][r] + bb;
        }
      }
    }
  }
}

// ---------------- causal flash attention (unchanged from R7) ----------------
__global__ __launch_bounds__(256, 2) void attn_kernel(
    const u16* __restrict__ Qb, const u16* __restrict__ Kb,
    const u16* __restrict__ Vt, u16* __restrict__ Ob) {
  __shared__ char Kls[4][8192];   // [buf][64 key rows][128B d]
  __shared__ char Vls[4][8192];   // [buf][64 d rows][128B keys]
  char* scratch = (char*)Kls;     // merge scratch (barrier-ordered reuse)

  const int id = blockIdx.x + 16 * blockIdx.y;
  const int s_ = id >> 3;
  const int bh = (id & 7) + 8 * (s_ % 3);  // same-bh blocks share an XCD
  const int xq = s_ / 3;                   // 0..15
  const int b = bh / 12, h = bh - b * 12;
  const int tid = threadIdx.x, w = tid >> 6, l = tid & 63;
  const int lq = l & 31, hi = l >> 5;
  const int qhalf = w & 1, grp = w >> 1;

  const u16* kbase = Kb + (size_t)(b * 2048) * 768 + h * 64;
  const u16* vbase = Vt + (size_t)(bh * 64) * 2048;

  const int r8 = l >> 3;
  const int scol8 = (l & 7) ^ r8;
  const u16* ksrc = kbase + (size_t)(w * 16 + r8) * 768 + scol8 * 8;
  const u16* vsrc = vbase + (size_t)(w * 16 + r8) * 2048 + scol8 * 8;

#define STAGE(t, bi)                                                        \
  {                                                                         \
    const size_t ko = (size_t)(t) * 64 * 768;                               \
    const int vo = (t) * 64;                                                \
    GLOAD16(ksrc + ko,            &Kls[bi][w * 2048]);                      \
    GLOAD16(ksrc + ko + 8 * 768,  &Kls[bi][w * 2048 + 1024]);               \
    GLOAD16(vsrc + vo,            &Vls[bi][w * 2048]);                      \
    GLOAD16(vsrc + vo + 8 * 2048, &Vls[bi][w * 2048 + 1024]);               \
  }

  const int fswz = (lq & 7) << 4;  // fragment-read XOR swizzle

#pragma unroll 1
  for (int half = 0; half < 2; half++) {
    const int qblk = half == 0 ? 31 - xq : xq;
    const int n = qblk + 1;          // kv tiles this phase
    const int nsup = (n + 1) >> 1;   // super-iterations

    bf16x8 qf[4];
    {
      const u16* qp = Qb + ((size_t)(b * 2048 + qblk * 64 + qhalf * 32 + lq)) * 768 +
                      h * 64 + hi * 8;
#pragma unroll
      for (int c = 0; c < 4; c++) qf[c] = *(const bf16x8*)(qp + c * 16);
    }

    float m_run = -INFINITY, l_run = 0.f;
    f32x16 acc2[2];
    acc2[0] = (f32x16)0.0f;
    acc2[1] = (f32x16)0.0f;

    STAGE(0, 0);
    if (n > 1) STAGE(1, 1);

    for (int p = 0; p < nsup; p++) {
      const int t0 = 2 * p;
      asm volatile("s_waitcnt vmcnt(0)" ::: "memory");  // tiles t0, t0+1 landed
      __builtin_amdgcn_s_barrier();
      __builtin_amdgcn_sched_barrier(0);
      if (t0 + 2 < n) STAGE(t0 + 2, (t0 + 2) & 3);
      if (t0 + 3 < n) STAGE(t0 + 3, (t0 + 3) & 3);

      const int tile = t0 + grp;
      if (tile < n) {
        const int cur = tile & 3;

        f32x16 s2[2];
        s2[0] = (f32x16)0.0f;
        s2[1] = (f32x16)0.0f;
        __builtin_amdgcn_s_setprio(1);
#pragma unroll
        for (int c = 0; c < 4; c++) {
          const int cb = (c * 32 + hi * 16) ^ fswz;
          bf16x8 kf0 = *(const bf16x8*)(&Kls[cur][lq * 128] + cb);
          bf16x8 kf1 = *(const bf16x8*)(&Kls[cur][(32 + lq) * 128] + cb);
          s2[0] = MFMA32(kf0, qf[c], s2[0]);
          s2[1] = MFMA32(kf1, qf[c], s2[1]);
        }
        __builtin_amdgcn_s_setprio(0);

        if (tile == qblk) {  // causal mask inside diagonal tile
          const int qrel = qhalf * 32 + lq;
#pragma unroll
          for (int kt2 = 0; kt2 < 2; kt2++)
#pragma unroll
            for (int r = 0; r < 16; r++) {
              const int ko = kt2 * 32 + (r & 3) + 8 * (r >> 2) + 4 * hi;
              if (ko > qrel) s2[kt2][r] = -INFINITY;
            }
        }

        float pm = s2[0][0];
#pragma unroll
        for (int r = 1; r < 16; r++) pm = fmaxf(pm, s2[0][r]);
#pragma unroll
        for (int r = 0; r < 16; r++) pm = fmaxf(pm, s2[1][r]);
        pm = fmaxf(pm, __shfl_xor(pm, 32));

        const float mn = fmaxf(m_run, pm);
        const float alpha = __expf(m_run - mn);
        m_run = mn;

        float rs = 0.f;
        u32 pk[2][8];
#pragma unroll
        for (int kt2 = 0; kt2 < 2; kt2++)
#pragma unroll
          for (int j = 0; j < 8; j++) {
            float p0 = __expf(s2[kt2][2 * j] - mn);
            float p1 = __expf(s2[kt2][2 * j + 1] - mn);
            rs += p0 + p1;
            asm("v_cvt_pk_bf16_f32 %0, %1, %2" : "=v"(pk[kt2][j]) : "v"(p0), "v"(p1));
          }
        l_run = l_run * alpha + rs;

        union { u32 u[4]; bf16x8 v; } pf[4];
#pragma unroll
        for (int kq = 0; kq < 4; kq++) {
          const int kt2 = kq >> 1, i0 = 4 * (kq & 1);
          u32 a0 = pk[kt2][i0], b0 = pk[kt2][i0 + 2];
          u32 a1 = pk[kt2][i0 + 1], b1 = pk[kt2][i0 + 3];
          asm("v_permlane32_swap_b32 %0, %1" : "+v"(a0), "+v"(b0));
          asm("v_permlane32_swap_b32 %0, %1" : "+v"(a1), "+v"(b1));
          pf[kq].u[0] = a0; pf[kq].u[1] = a1; pf[kq].u[2] = b0; pf[kq].u[3] = b1;
        }

#pragma unroll
        for (int dh = 0; dh < 2; dh++)
#pragma unroll
          for (int r = 0; r < 16; r++) acc2[dh][r] *= alpha;

        __builtin_amdgcn_s_setprio(1);
#pragma unroll
        for (int dh = 0; dh < 2; dh++) {
          const char* vr = &Vls[cur][(dh * 32 + lq) * 128];
#pragma unroll
          for (int kq = 0; kq < 4; kq++) {
            bf16x8 vf = *(const bf16x8*)(vr + ((kq * 32 + hi * 16) ^ fswz));
            acc2[dh] = MFMA32(vf, pf[kq].v, acc2[dh]);
          }
        }
        __builtin_amdgcn_s_setprio(0);
      }
    }

    // ---- merge the two kv-groups via LDS scratch ----
    asm volatile("s_waitcnt lgkmcnt(0)" ::: "memory");
    __builtin_amdgcn_s_barrier();  // A: all compute (and LDS reads) done
    if (grp == 1) {
      float* sc = (float*)scratch + ((size_t)(w - 2) * 64 + l) * 34;
#pragma unroll
      for (int dh = 0; dh < 2; dh++)
#pragma unroll
        for (int r = 0; r < 16; r++) sc[dh * 16 + r] = acc2[dh][r];
      sc[32] = m_run;
      sc[33] = l_run;
    }
    asm volatile("s_waitcnt lgkmcnt(0)" ::: "memory");
    __builtin_amdgcn_s_barrier();  // B: group-1 state visible
    if (grp == 0) {
      const float* sc = (const float*)scratch + ((size_t)w * 64 + l) * 34;
      const float m1 = sc[32], l1 = sc[33];
      const float M = fmaxf(m_run, m1);
      const float a0 = __expf(m_run - M);
      const float a1 = __expf(m1 - M);   // exp(-inf - finite) = 0 when group1 idle
      const float lm = l_run * a0 + l1 * a1;
      const float lt = lm + __shfl_xor(lm, 32);
      const float inv = 1.0f / lt;
      u16* ob = Ob + ((size_t)(b * 2048 + qblk * 64 + qhalf * 32 + lq)) * 768 + h * 64;
#pragma unroll
      for (int dh = 0; dh < 2; dh++)
#pragma unroll
        for (int g = 0; g < 4; g++) {
          ushort4 o4;
          o4.x = f2bf((acc2[dh][4 * g + 0] * a0 + sc[dh * 16 + 4 * g + 0] * a1) * inv);
          o4.y = f2bf((acc2[dh][4 * g + 1] * a0 + sc[dh * 16 + 4 * g + 1] * a1) * inv);
          o4.z = f2bf((acc2[dh][4 * g + 2] * a0 + sc[dh * 16 + 4 * g + 2] * a1) * inv);
          o4.w = f2bf((acc2[dh][4 * g + 3] * a0 + sc[dh * 16 + 4 * g + 3] * a1) * inv);
          *(ushort4*)(ob + dh * 32 + 8 * g + 4 * hi) = o4;
        }
    }
    asm volatile("s_waitcnt lgkmcnt(0)" ::: "memory");
    __builtin_amdgcn_s_barrier();  // C: scratch reads done before next-phase staging
  }
#undef STAGE
}

// ---------------- launcher ----------------

extern "C" void kernel_launch(void* const* d_in, const int* in_sizes, int n_in,
                              void* d_out, int out_size, void* d_ws, size_t ws_size,
                              hipStream_t stream) {
  const float* x  = (const float*)d_in[0];
  const float* WQ = (const float*)d_in[1];
  const float* bQ = (const float*)d_in[2];
  const float* WK = (const float*)d_in[3];
  const float* bK = (const float*)d_in[4];
  const float* WV = (const float*)d_in[5];
  const float* bV = (const float*)d_in[6];
  const float* WO = (const float*)d_in[7];
  const float* bO = (const float*)d_in[8];

  char* ws = (char*)d_ws;
  u16* Xb    = (u16*)(ws + 0);          // 4096x768 bf16
  u16* Wqkv  = (u16*)(ws + 6291456);    // 2304x768 bf16 (B^T)
  u16* WoT   = (u16*)(ws + 9830400);    // 768x768 bf16 (B^T)
  u16* Qb    = (u16*)(ws + 11010048);   // [B][T][768] bf16
  u16* Kb    = (u16*)(ws + 17301504);   // [B][T][768] bf16
  u16* Vt    = (u16*)(ws + 23592960);   // [bh][64][2048] bf16
  u16* Ob    = (u16*)(ws + 29884416);   // [B*T][768] bf16
  float* cost = (float*)(ws + 36175872); // [2048][32]
  float* sint = (float*)(ws + 36438016); // [2048][32]

  rope_tables<<<256, 256, 0, stream>>>(cost, sint);
  cast_x<<<3072, 256, 0, stream>>>(x, Xb, 4096 * 768);
  prep_wqkv<<<dim3(24, 2, 36), dim3(32, 8), 0, stream>>>(WQ, WK, WV, Wqkv);
  prep_wo<<<dim3(24, 24), dim3(32, 8), 0, stream>>>(WO, WoT);

  gemm_bt<0><<<dim3(32, 18), 256, 0, stream>>>(Xb, Wqkv, 768, 768, 768,
                                               bQ, bK, bV, cost, sint,
                                               Qb, Kb, Vt, nullptr, nullptr);
  attn_kernel<<<dim3(16, 24), 256, 0, stream>>>(Qb, Kb, Vt, Ob);
  gemm_bt<1><<<dim3(32, 6), 256, 0, stream>>>(Ob, WoT, 768, 768, 768,
                                              nullptr, nullptr, nullptr, nullptr, nullptr,
                                              nullptr, nullptr, nullptr, bO, (float*)d_out);
}

// Round 9
// 107.286 us; speedup vs baseline: 2.3875x; 1.0791x over previous
//
#include <hip/hip_runtime.h>

typedef unsigned short u16;
typedef unsigned int u32;
typedef short bf16x8 __attribute__((ext_vector_type(8)));
typedef float f32x4 __attribute__((ext_vector_type(4)));
typedef float f32x16 __attribute__((ext_vector_type(16)));

#define MFMA(a, b, c) __builtin_amdgcn_mfma_f32_16x16x32_bf16(a, b, c, 0, 0, 0)
#define MFMA32(a, b, c) __builtin_amdgcn_mfma_f32_32x32x16_bf16(a, b, c, 0, 0, 0)

// f32 -> bf16 round-to-nearest-even
__device__ __forceinline__ u16 f2bf(float f) {
  unsigned int u = __float_as_uint(f);
  u = (u + 0x7FFFu + ((u >> 16) & 1u)) >> 16;
  return (u16)u;
}

// async global->LDS, 16B per lane; lds dest must be wave-uniform base (HW adds lane*16)
#define GLOAD16(gp, lp)                                                        \
  __builtin_amdgcn_global_load_lds(                                            \
      (const __attribute__((address_space(1))) void*)(gp),                     \
      (__attribute__((address_space(3))) void*)(lp), 16, 0, 0)

// ---------------- fused prep kernel ----------------
// block ranges: [0,256) rope tables | [256,3328) cast x | [3328,5056) Wqkv^T | [5056,5632) Wo^T
__global__ __launch_bounds__(256) void prep_all(
    const float* __restrict__ x, const float* __restrict__ WQ,
    const float* __restrict__ WK, const float* __restrict__ WV,
    const float* __restrict__ WO, float* __restrict__ cost, float* __restrict__ sint,
    u16* __restrict__ xb, u16* __restrict__ Wt, u16* __restrict__ WoT) {
  __shared__ float tile[32][33];
  const int bid = blockIdx.x, tid = threadIdx.x;

  if (bid < 256) {  // rope tables (2048 x 32)
    int idx = bid * 256 + tid;
    int t = idx >> 5, i = idx & 31;
    float invf = expf(-(float)i * 0.28782313662425572f);
    float ang = (float)t * invf;
    cost[idx] = cosf(ang);
    sint[idx] = sinf(ang);
  } else if (bid < 3328) {  // cast x (4096*768 f32 -> bf16, 4/thread)
    int i = ((bid - 256) * 256 + tid) * 4;
    float4 v = *(const float4*)(x + i);
    ushort4 o = make_ushort4(f2bf(v.x), f2bf(v.y), f2bf(v.z), f2bf(v.w));
    *(ushort4*)(xb + i) = o;
  } else if (bid < 5056) {  // Wqkv transpose: Wt[qkv*768+h*64+d][c] = W[h][c][d]
    const int pbid = bid - 3328;                  // 0..1727
    const int z = pbid / 48, rem = pbid - z * 48; // z 0..35
    const int y = rem / 24, xk = rem - y * 24;    // y 0..1, xk 0..23
    const int qkv = z / 12, h = z - qkv * 12;
    const float* W = (qkv == 0 ? WQ : qkv == 1 ? WK : WV) + (size_t)h * 768 * 64;
    const int k0 = xk * 32, d0 = y * 32;
    const int tx = tid & 31, ty = tid >> 5;
#pragma unroll
    for (int it = 0; it < 4; it++)
      tile[ty + it * 8][tx] = W[(size_t)(k0 + ty + it * 8) * 64 + d0 + tx];
    __syncthreads();
    u16* out = Wt + (size_t)(qkv * 768 + h * 64 + d0) * 768 + k0;
#pragma unroll
    for (int it = 0; it < 4; it++)
      out[(size_t)(ty + it * 8) * 768 + tx] = f2bf(tile[tx][ty + it * 8]);
  } else {  // Wo transpose: WoT[m][hd] = WO[hd][m]
    const int wbid = bid - 5056;  // 0..575
    const int a0 = (wbid % 24) * 32, m0 = (wbid / 24) * 32;
    const int tx = tid & 31, ty = tid >> 5;
#pragma unroll
    for (int it = 0; it < 4; it++)
      tile[ty + it * 8][tx] = WO[(size_t)(a0 + ty + it * 8) * 768 + m0 + tx];
    __syncthreads();
#pragma unroll
    for (int it = 0; it < 4; it++)
      WoT[(size_t)(m0 + ty + it * 8) * 768 + a0 + tx] = f2bf(tile[tx][ty + it * 8]);
  }
}

// ---------------- GEMM (64x128 tile, BK=32, deep-pipelined) ----------------
// 4 waves (2 m-halves x 2 n-halves, each 32x64), 8 MFMA/wave/iter. 3 LDS buffers,
// prefetch depth 2, one s_barrier/iter + counted vmcnt(3). Grid 1152 (gemm0) =
// 4.5 blocks/CU (was 2.25: grid-starved). LDS 36KB -> 4 blocks/CU capacity.
// Swizzle rule #21 as in R8 (verified conflict-free). XCD m-chunking: 1D grid,
// id&7 = xcd owns 8 consecutive m-blocks across all n.
template <int MODE>
__global__ __launch_bounds__(256) void gemm_bt(
    const u16* __restrict__ A, const u16* __restrict__ Bt, int K, int LDA, int LDB,
    const float* __restrict__ bQ, const float* __restrict__ bK, const float* __restrict__ bV,
    const float* __restrict__ cost, const float* __restrict__ sint,
    u16* __restrict__ Qb, u16* __restrict__ Kb, u16* __restrict__ Vt,
    const float* __restrict__ bO, float* __restrict__ Out) {
  __shared__ u16 As[3][64 * 32];
  __shared__ u16 Bs[3][128 * 32];
  const int tid = threadIdx.x;
  const int w = tid >> 6, l = tid & 63;
  const int lr = l >> 4, lc = l & 15;
  const int wr = w >> 1, wc = w & 1;

  const int id = blockIdx.x;
  const int xcd = id & 7, idx = id >> 3;
  const int m0 = (xcd * 8 + (idx & 7)) * 64;
  const int n0 = (idx >> 3) * 128;

  f32x4 acc[2][4];
#pragma unroll
  for (int mi = 0; mi < 2; mi++)
#pragma unroll
    for (int ni = 0; ni < 4; ni++) acc[mi][ni] = (f32x4){0.f, 0.f, 0.f, 0.f};

  // staging: thread covers row w*16+(l>>2); src granule (l&3)^((l>>3)&3)
  const int srow = w * 16 + (l >> 2);
  const int sg = (l & 3) ^ ((l >> 3) & 3);
  const u16* ga = A + (size_t)(m0 + srow) * LDA + sg * 8;
  const u16* gb = Bt + (size_t)(n0 + srow) * LDB + sg * 8;

#define GSTAGE(t, bi)                                                   \
  {                                                                     \
    const int kk = (t) * 32;                                            \
    GLOAD16(ga + kk, &As[bi][w * 512]);                                 \
    GLOAD16(gb + kk, &Bs[bi][w * 512]);                                 \
    GLOAD16(gb + kk + (size_t)64 * LDB, &Bs[bi][2048 + w * 512]);       \
  }

  const int n = K >> 5;
  GSTAGE(0, 0);
  if (n > 1) GSTAGE(1, 1);

  for (int kt = 0; kt < n; kt++) {
    if (kt + 1 < n) asm volatile("s_waitcnt vmcnt(3)" ::: "memory");
    else            asm volatile("s_waitcnt vmcnt(0)" ::: "memory");
    __builtin_amdgcn_s_barrier();
    __builtin_amdgcn_sched_barrier(0);
    if (kt + 2 < n) GSTAGE(kt + 2, (kt + 2) % 3);

    const char* as = (const char*)As[kt % 3];
    const char* bs = (const char*)Bs[kt % 3];
    bf16x8 af[2], bfr[4];
#pragma unroll
    for (int mi = 0; mi < 2; mi++) {
      const int row = wr * 32 + mi * 16 + lc;
      af[mi] = *(const bf16x8*)(as + row * 64 + ((lr ^ ((row >> 1) & 3)) << 4));
    }
#pragma unroll
    for (int ni = 0; ni < 4; ni++) {
      const int row = wc * 64 + ni * 16 + lc;
      bfr[ni] = *(const bf16x8*)(bs + row * 64 + ((lr ^ ((row >> 1) & 3)) << 4));
    }
    __builtin_amdgcn_s_setprio(1);
#pragma unroll
    for (int mi = 0; mi < 2; mi++)
#pragma unroll
      for (int ni = 0; ni < 4; ni++)
        acc[mi][ni] = MFMA(af[mi], bfr[ni], acc[mi][ni]);
    __builtin_amdgcn_s_setprio(0);
    // no trailing barrier: next iteration's vmcnt+barrier fences buffer reuse
  }
#undef GSTAGE

#pragma unroll
  for (int mi = 0; mi < 2; mi++) {
#pragma unroll
    for (int ni = 0; ni < 4; ni++) {
      const int col = n0 + wc * 64 + ni * 16 + lc;
      const int rowb = m0 + wr * 32 + mi * 16 + lr * 4;
      if (MODE == 0) {
        const int qkv = col / 768;  // uniform per fragment (768 = 48*16)
        const int rem = col - qkv * 768;
        const int h = rem >> 6, d = rem & 63, fi = d >> 1;
        const float bb = (qkv == 0 ? bQ : qkv == 1 ? bK : bV)[rem];
#pragma unroll
        for (int r = 0; r < 4; r++) {
          const int grow = rowb + r;
          const int t = grow & 2047;
          float v = acc[mi][ni][r] + bb;
          float pv = __shfl_xor(v, 1);  // partner of the rope pair (adjacent col)
          if (qkv < 2) {
            const float c = cost[t * 32 + fi], s = sint[t * 32 + fi];
            float o = (d & 1) ? (pv * s + v * c) : (v * c - pv * s);
            if (qkv == 0) o *= 0.125f;  // fold 1/sqrt(64) into Q
            (qkv == 0 ? Qb : Kb)[(size_t)grow * 768 + rem] = f2bf(o);
          } else {
            const int bidx = grow >> 11;
            Vt[((size_t)(bidx * 12 + h) * 64 + d) * 2048 + t] = f2bf(v);
          }
        }
      } else {
        const float bb = bO[col];
#pragma unroll
        for (int r = 0; r < 4; r++) {
          const int grow = rowb + r;
          Out[(size_t)grow * 768 + col] = acc[mi][ni][r] + bb;
        }
      }
    }
  }
}

// ---------------- causal flash attention (unchanged from R7) ----------------
__global__ __launch_bounds__(256, 2) void attn_kernel(
    const u16* __restrict__ Qb, const u16* __restrict__ Kb,
    const u16* __restrict__ Vt, u16* __restrict__ Ob) {
  __shared__ char Kls[4][8192];   // [buf][64 key rows][128B d]
  __shared__ char Vls[4][8192];   // [buf][64 d rows][128B keys]
  char* scratch = (char*)Kls;     // merge scratch (barrier-ordered reuse)

  const int id = blockIdx.x + 16 * blockIdx.y;
  const int s_ = id >> 3;
  const int bh = (id & 7) + 8 * (s_ % 3);  // same-bh blocks share an XCD
  const int xq = s_ / 3;                   // 0..15
  const int b = bh / 12, h = bh - b * 12;
  const int tid = threadIdx.x, w = tid >> 6, l = tid & 63;
  const int lq = l & 31, hi = l >> 5;
  const int qhalf = w & 1, grp = w >> 1;

  const u16* kbase = Kb + (size_t)(b * 2048) * 768 + h * 64;
  const u16* vbase = Vt + (size_t)(bh * 64) * 2048;

  const int r8 = l >> 3;
  const int scol8 = (l & 7) ^ r8;
  const u16* ksrc = kbase + (size_t)(w * 16 + r8) * 768 + scol8 * 8;
  const u16* vsrc = vbase + (size_t)(w * 16 + r8) * 2048 + scol8 * 8;

#define STAGE(t, bi)                                                        \
  {                                                                         \
    const size_t ko = (size_t)(t) * 64 * 768;                               \
    const int vo = (t) * 64;                                                \
    GLOAD16(ksrc + ko,            &Kls[bi][w * 2048]);                      \
    GLOAD16(ksrc + ko + 8 * 768,  &Kls[bi][w * 2048 + 1024]);               \
    GLOAD16(vsrc + vo,            &Vls[bi][w * 2048]);                      \
    GLOAD16(vsrc + vo + 8 * 2048, &Vls[bi][w * 2048 + 1024]);               \
  }

  const int fswz = (lq & 7) << 4;  // fragment-read XOR swizzle

#pragma unroll 1
  for (int half = 0; half < 2; half++) {
    const int qblk = half == 0 ? 31 - xq : xq;
    const int n = qblk + 1;          // kv tiles this phase
    const int nsup = (n + 1) >> 1;   // super-iterations

    bf16x8 qf[4];
    {
      const u16* qp = Qb + ((size_t)(b * 2048 + qblk * 64 + qhalf * 32 + lq)) * 768 +
                      h * 64 + hi * 8;
#pragma unroll
      for (int c = 0; c < 4; c++) qf[c] = *(const bf16x8*)(qp + c * 16);
    }

    float m_run = -INFINITY, l_run = 0.f;
    f32x16 acc2[2];
    acc2[0] = (f32x16)0.0f;
    acc2[1] = (f32x16)0.0f;

    STAGE(0, 0);
    if (n > 1) STAGE(1, 1);

    for (int p = 0; p < nsup; p++) {
      const int t0 = 2 * p;
      asm volatile("s_waitcnt vmcnt(0)" ::: "memory");  // tiles t0, t0+1 landed
      __builtin_amdgcn_s_barrier();
      __builtin_amdgcn_sched_barrier(0);
      if (t0 + 2 < n) STAGE(t0 + 2, (t0 + 2) & 3);
      if (t0 + 3 < n) STAGE(t0 + 3, (t0 + 3) & 3);

      const int tile = t0 + grp;
      if (tile < n) {
        const int cur = tile & 3;

        f32x16 s2[2];
        s2[0] = (f32x16)0.0f;
        s2[1] = (f32x16)0.0f;
        __builtin_amdgcn_s_setprio(1);
#pragma unroll
        for (int c = 0; c < 4; c++) {
          const int cb = (c * 32 + hi * 16) ^ fswz;
          bf16x8 kf0 = *(const bf16x8*)(&Kls[cur][lq * 128] + cb);
          bf16x8 kf1 = *(const bf16x8*)(&Kls[cur][(32 + lq) * 128] + cb);
          s2[0] = MFMA32(kf0, qf[c], s2[0]);
          s2[1] = MFMA32(kf1, qf[c], s2[1]);
        }
        __builtin_amdgcn_s_setprio(0);

        if (tile == qblk) {  // causal mask inside diagonal tile
          const int qrel = qhalf * 32 + lq;
#pragma unroll
          for (int kt2 = 0; kt2 < 2; kt2++)
#pragma unroll
            for (int r = 0; r < 16; r++) {
              const int ko = kt2 * 32 + (r & 3) + 8 * (r >> 2) + 4 * hi;
              if (ko > qrel) s2[kt2][r] = -INFINITY;
            }
        }

        float pm = s2[0][0];
#pragma unroll
        for (int r = 1; r < 16; r++) pm = fmaxf(pm, s2[0][r]);
#pragma unroll
        for (int r = 0; r < 16; r++) pm = fmaxf(pm, s2[1][r]);
        pm = fmaxf(pm, __shfl_xor(pm, 32));

        const float mn = fmaxf(m_run, pm);
        const float alpha = __expf(m_run - mn);
        m_run = mn;

        float rs = 0.f;
        u32 pk[2][8];
#pragma unroll
        for (int kt2 = 0; kt2 < 2; kt2++)
#pragma unroll
          for (int j = 0; j < 8; j++) {
            float p0 = __expf(s2[kt2][2 * j] - mn);
            float p1 = __expf(s2[kt2][2 * j + 1] - mn);
            rs += p0 + p1;
            asm("v_cvt_pk_bf16_f32 %0, %1, %2" : "=v"(pk[kt2][j]) : "v"(p0), "v"(p1));
          }
        l_run = l_run * alpha + rs;

        union { u32 u[4]; bf16x8 v; } pf[4];
#pragma unroll
        for (int kq = 0; kq < 4; kq++) {
          const int kt2 = kq >> 1, i0 = 4 * (kq & 1);
          u32 a0 = pk[kt2][i0], b0 = pk[kt2][i0 + 2];
          u32 a1 = pk[kt2][i0 + 1], b1 = pk[kt2][i0 + 3];
          asm("v_permlane32_swap_b32 %0, %1" : "+v"(a0), "+v"(b0));
          asm("v_permlane32_swap_b32 %0, %1" : "+v"(a1), "+v"(b1));
          pf[kq].u[0] = a0; pf[kq].u[1] = a1; pf[kq].u[2] = b0; pf[kq].u[3] = b1;
        }

#pragma unroll
        for (int dh = 0; dh < 2; dh++)
#pragma unroll
          for (int r = 0; r < 16; r++) acc2[dh][r] *= alpha;

        __builtin_amdgcn_s_setprio(1);
#pragma unroll
        for (int dh = 0; dh < 2; dh++) {
          const char* vr = &Vls[cur][(dh * 32 + lq) * 128];
#pragma unroll
          for (int kq = 0; kq < 4; kq++) {
            bf16x8 vf = *(const bf16x8*)(vr + ((kq * 32 + hi * 16) ^ fswz));
            acc2[dh] = MFMA32(vf, pf[kq].v, acc2[dh]);
          }
        }
        __builtin_amdgcn_s_setprio(0);
      }
    }

    // ---- merge the two kv-groups via LDS scratch ----
    asm volatile("s_waitcnt lgkmcnt(0)" ::: "memory");
    __builtin_amdgcn_s_barrier();  // A: all compute (and LDS reads) done
    if (grp == 1) {
      float* sc = (float*)scratch + ((size_t)(w - 2) * 64 + l) * 34;
#pragma unroll
      for (int dh = 0; dh < 2; dh++)
#pragma unroll
        for (int r = 0; r < 16; r++) sc[dh * 16 + r] = acc2[dh][r];
      sc[32] = m_run;
      sc[33] = l_run;
    }
    asm volatile("s_waitcnt lgkmcnt(0)" ::: "memory");
    __builtin_amdgcn_s_barrier();  // B: group-1 state visible
    if (grp == 0) {
      const float* sc = (const float*)scratch + ((size_t)w * 64 + l) * 34;
      const float m1 = sc[32], l1 = sc[33];
      const float M = fmaxf(m_run, m1);
      const float a0 = __expf(m_run - M);
      const float a1 = __expf(m1 - M);   // exp(-inf - finite) = 0 when group1 idle
      const float lm = l_run * a0 + l1 * a1;
      const float lt = lm + __shfl_xor(lm, 32);
      const float inv = 1.0f / lt;
      u16* ob = Ob + ((size_t)(b * 2048 + qblk * 64 + qhalf * 32 + lq)) * 768 + h * 64;
#pragma unroll
      for (int dh = 0; dh < 2; dh++)
#pragma unroll
        for (int g = 0; g < 4; g++) {
          ushort4 o4;
          o4.x = f2bf((acc2[dh][4 * g + 0] * a0 + sc[dh * 16 + 4 * g + 0] * a1) * inv);
          o4.y = f2bf((acc2[dh][4 * g + 1] * a0 + sc[dh * 16 + 4 * g + 1] * a1) * inv);
          o4.z = f2bf((acc2[dh][4 * g + 2] * a0 + sc[dh * 16 + 4 * g + 2] * a1) * inv);
          o4.w = f2bf((acc2[dh][4 * g + 3] * a0 + sc[dh * 16 + 4 * g + 3] * a1) * inv);
          *(ushort4*)(ob + dh * 32 + 8 * g + 4 * hi) = o4;
        }
    }
    asm volatile("s_waitcnt lgkmcnt(0)" ::: "memory");
    __builtin_amdgcn_s_barrier();  // C: scratch reads done before next-phase staging
  }
#undef STAGE
}

// ---------------- launcher ----------------

extern "C" void kernel_launch(void* const* d_in, const int* in_sizes, int n_in,
                              void* d_out, int out_size, void* d_ws, size_t ws_size,
                              hipStream_t stream) {
  const float* x  = (const float*)d_in[0];
  const float* WQ = (const float*)d_in[1];
  const float* bQ = (const float*)d_in[2];
  const float* WK = (const float*)d_in[3];
  const float* bK = (const float*)d_in[4];
  const float* WV = (const float*)d_in[5];
  const float* bV = (const float*)d_in[6];
  const float* WO = (const float*)d_in[7];
  const float* bO = (const float*)d_in[8];

  char* ws = (char*)d_ws;
  u16* Xb    = (u16*)(ws + 0);          // 4096x768 bf16
  u16* Wqkv  = (u16*)(ws + 6291456);    // 2304x768 bf16 (B^T)
  u16* WoT   = (u16*)(ws + 9830400);    // 768x768 bf16 (B^T)
  u16* Qb    = (u16*)(ws + 11010048);   // [B][T][768] bf16
  u16* Kb    = (u16*)(ws + 17301504);   // [B][T][768] bf16
  u16* Vt    = (u16*)(ws + 23592960);   // [bh][64][2048] bf16
  u16* Ob    = (u16*)(ws + 29884416);   // [B*T][768] bf16
  float* cost = (float*)(ws + 36175872); // [2048][32]
  float* sint = (float*)(ws + 36438016); // [2048][32]

  prep_all<<<5632, 256, 0, stream>>>(x, WQ, WK, WV, WO, cost, sint, Xb, Wqkv, WoT);

  gemm_bt<0><<<1152, 256, 0, stream>>>(Xb, Wqkv, 768, 768, 768,
                                       bQ, bK, bV, cost, sint,
                                       Qb, Kb, Vt, nullptr, nullptr);
  attn_kernel<<<dim3(16, 24), 256, 0, stream>>>(Qb, Kb, Vt, Ob);
  gemm_bt<1><<<384, 256, 0, stream>>>(Ob, WoT, 768, 768, 768,
                                      nullptr, nullptr, nullptr, nullptr, nullptr,
                                      nullptr, nullptr, nullptr, bO, (float*)d_out);
}

// Round 10
// 105.891 us; speedup vs baseline: 2.4190x; 1.0132x over previous
//
#include <hip/hip_runtime.h>

typedef unsigned short u16;
typedef unsigned int u32;
typedef short bf16x8 __attribute__((ext_vector_type(8)));
typedef float f32x4 __attribute__((ext_vector_type(4)));
typedef float f32x16 __attribute__((ext_vector_type(16)));

#define MFMA(a, b, c) __builtin_amdgcn_mfma_f32_16x16x32_bf16(a, b, c, 0, 0, 0)
#define MFMA32(a, b, c) __builtin_amdgcn_mfma_f32_32x32x16_bf16(a, b, c, 0, 0, 0)

// f32 -> bf16 round-to-nearest-even
__device__ __forceinline__ u16 f2bf(float f) {
  unsigned int u = __float_as_uint(f);
  u = (u + 0x7FFFu + ((u >> 16) & 1u)) >> 16;
  return (u16)u;
}

// async global->LDS, 16B per lane; lds dest must be wave-uniform base (HW adds lane*16)
#define GLOAD16(gp, lp)                                                        \
  __builtin_amdgcn_global_load_lds(                                            \
      (const __attribute__((address_space(1))) void*)(gp),                     \
      (__attribute__((address_space(3))) void*)(lp), 16, 0, 0)

// ---------------- fused prep kernel ----------------
// block ranges: [0,256) rope tables | [256,3328) cast x | [3328,5056) Wqkv^T | [5056,5632) Wo^T
__global__ __launch_bounds__(256) void prep_all(
    const float* __restrict__ x, const float* __restrict__ WQ,
    const float* __restrict__ WK, const float* __restrict__ WV,
    const float* __restrict__ WO, float* __restrict__ cost, float* __restrict__ sint,
    u16* __restrict__ xb, u16* __restrict__ Wt, u16* __restrict__ WoT) {
  __shared__ float tile[32][33];
  const int bid = blockIdx.x, tid = threadIdx.x;

  if (bid < 256) {  // rope tables (2048 x 32)
    int idx = bid * 256 + tid;
    int t = idx >> 5, i = idx & 31;
    float invf = expf(-(float)i * 0.28782313662425572f);
    float ang = (float)t * invf;
    cost[idx] = cosf(ang);
    sint[idx] = sinf(ang);
  } else if (bid < 3328) {  // cast x (4096*768 f32 -> bf16, 4/thread)
    int i = ((bid - 256) * 256 + tid) * 4;
    float4 v = *(const float4*)(x + i);
    ushort4 o = make_ushort4(f2bf(v.x), f2bf(v.y), f2bf(v.z), f2bf(v.w));
    *(ushort4*)(xb + i) = o;
  } else if (bid < 5056) {  // Wqkv transpose: Wt[qkv*768+h*64+d][c] = W[h][c][d]
    const int pbid = bid - 3328;                  // 0..1727
    const int z = pbid / 48, rem = pbid - z * 48; // z 0..35
    const int y = rem / 24, xk = rem - y * 24;    // y 0..1, xk 0..23
    const int qkv = z / 12, h = z - qkv * 12;
    const float* W = (qkv == 0 ? WQ : qkv == 1 ? WK : WV) + (size_t)h * 768 * 64;
    const int k0 = xk * 32, d0 = y * 32;
    const int tx = tid & 31, ty = tid >> 5;
#pragma unroll
    for (int it = 0; it < 4; it++)
      tile[ty + it * 8][tx] = W[(size_t)(k0 + ty + it * 8) * 64 + d0 + tx];
    __syncthreads();
    u16* out = Wt + (size_t)(qkv * 768 + h * 64 + d0) * 768 + k0;
#pragma unroll
    for (int it = 0; it < 4; it++)
      out[(size_t)(ty + it * 8) * 768 + tx] = f2bf(tile[tx][ty + it * 8]);
  } else {  // Wo transpose: WoT[m][hd] = WO[hd][m]
    const int wbid = bid - 5056;  // 0..575
    const int a0 = (wbid % 24) * 32, m0 = (wbid / 24) * 32;
    const int tx = tid & 31, ty = tid >> 5;
#pragma unroll
    for (int it = 0; it < 4; it++)
      tile[ty + it * 8][tx] = WO[(size_t)(a0 + ty + it * 8) * 768 + m0 + tx];
    __syncthreads();
#pragma unroll
    for (int it = 0; it < 4; it++)
      WoT[(size_t)(m0 + ty + it * 8) * 768 + a0 + tx] = f2bf(tile[tx][ty + it * 8]);
  }
}

// ---------------- GEMM (128x128 tile, BK=32, in-block split-K, 512 thr) ----------------
// 8 waves = 2 k-parity groups x 4 waves (each 64x64). Group g computes k-tiles
// {g, g+2, ...} (12 each). 4 LDS buffers (64KB), 2 tiles staged per super-iter,
// ONE s_barrier + one vmcnt(0) per super (loads are a full super old -> no stall;
// overwritten buffers were consumed in super p-1, fenced by the barrier --
// the proven attn-R7 pipeline). Groups merge partial accs via LDS scratch
// (staging bufs reused, [j][thread] layout = conflict-free). Swizzle rule #21
// as R8 (verified conflicts=0). XCD m-chunking. Staging traffic = R8 (221MB),
// barrier count halved (12), waves/CU 16.
template <int MODE>
__global__ __launch_bounds__(512, 4) void gemm_bt(
    const u16* __restrict__ A, const u16* __restrict__ Bt, int K, int LDA, int LDB,
    const float* __restrict__ bQ, const float* __restrict__ bK, const float* __restrict__ bV,
    const float* __restrict__ cost, const float* __restrict__ sint,
    u16* __restrict__ Qb, u16* __restrict__ Kb, u16* __restrict__ Vt,
    const float* __restrict__ bO, float* __restrict__ Out) {
  __shared__ u16 SH[32768];  // 64KB: 4 bufs x (A 8KB + B 8KB); reused as merge scratch
#define AS_(bi) (&SH[(bi) * 8192])
#define BS_(bi) (&SH[(bi) * 8192 + 4096])
  const int tid = threadIdx.x;
  const int w = tid >> 6, l = tid & 63;
  const int grp = w >> 2, wsub = w & 3;
  const int lr = l >> 4, lc = l & 15;
  const int wr = wsub >> 1, wc = wsub & 1;

  const int id = blockIdx.x;
  const int xcd = id & 7, idx = id >> 3;
  const int m0 = (xcd * 4 + (idx & 3)) * 128;
  const int n0 = (idx >> 2) * 128;

  f32x4 acc[4][4];
#pragma unroll
  for (int mi = 0; mi < 4; mi++)
#pragma unroll
    for (int ni = 0; ni < 4; ni++) acc[mi][ni] = (f32x4){0.f, 0.f, 0.f, 0.f};

  // staging: 512 threads cover 128 rows x 64B per matrix; thread -> row tid>>2,
  // source granule (tid&3)^((tid>>3)&3) (pre-swizzle matching the read XOR)
  const int srow = tid >> 2;
  const int sg = (tid & 3) ^ ((tid >> 3) & 3);
  const u16* ga = A + (size_t)(m0 + srow) * LDA + sg * 8;
  const u16* gb = Bt + (size_t)(n0 + srow) * LDB + sg * 8;

#define GSTAGE(t, bi)                                                   \
  {                                                                     \
    const int kk = (t) * 32;                                            \
    GLOAD16(ga + kk, &AS_(bi)[w * 512]);                                \
    GLOAD16(gb + kk, &BS_(bi)[w * 512]);                                \
  }

  const int nt = K >> 5;        // 24
  const int nsup = nt >> 1;     // 12
  GSTAGE(0, 0);
  GSTAGE(1, 1);

  for (int p = 0; p < nsup; p++) {
    asm volatile("s_waitcnt vmcnt(0)" ::: "memory");  // tiles 2p,2p+1 landed (1 super old)
    __builtin_amdgcn_s_barrier();
    __builtin_amdgcn_sched_barrier(0);
    if (2 * p + 2 < nt) GSTAGE(2 * p + 2, (2 * p + 2) & 3);
    if (2 * p + 3 < nt) GSTAGE(2 * p + 3, (2 * p + 3) & 3);

    const int tile = 2 * p + grp;
    const char* as = (const char*)AS_(tile & 3);
    const char* bs = (const char*)BS_(tile & 3);
    bf16x8 af[4], bfr[4];
#pragma unroll
    for (int mi = 0; mi < 4; mi++) {
      const int row = wr * 64 + mi * 16 + lc;
      af[mi] = *(const bf16x8*)(as + row * 64 + ((lr ^ ((row >> 1) & 3)) << 4));
    }
#pragma unroll
    for (int ni = 0; ni < 4; ni++) {
      const int row = wc * 64 + ni * 16 + lc;
      bfr[ni] = *(const bf16x8*)(bs + row * 64 + ((lr ^ ((row >> 1) & 3)) << 4));
    }
    __builtin_amdgcn_s_setprio(1);
#pragma unroll
    for (int mi = 0; mi < 4; mi++)
#pragma unroll
      for (int ni = 0; ni < 4; ni++)
        acc[mi][ni] = MFMA(af[mi], bfr[ni], acc[mi][ni]);
    __builtin_amdgcn_s_setprio(0);
  }
#undef GSTAGE

  // ---- merge the two k-groups via LDS scratch (staging bufs, now idle) ----
  asm volatile("s_waitcnt vmcnt(0)" ::: "memory");
  __builtin_amdgcn_s_barrier();  // all compute + staging done
  float* sc = (float*)SH;        // [j 0..15][thread 0..255] f32x4: j*4096B + t*16B
  const int t8 = (wsub << 6) | l;
  if (grp == 1) {
#pragma unroll
    for (int mi = 0; mi < 4; mi++)
#pragma unroll
      for (int ni = 0; ni < 4; ni++)
        *(f32x4*)((char*)sc + (mi * 4 + ni) * 4096 + t8 * 16) = acc[mi][ni];
  }
  asm volatile("s_waitcnt lgkmcnt(0)" ::: "memory");
  __builtin_amdgcn_s_barrier();  // group-1 partials visible
  if (grp == 0) {
#pragma unroll
    for (int mi = 0; mi < 4; mi++)
#pragma unroll
      for (int ni = 0; ni < 4; ni++) {
        f32x4 o = *(const f32x4*)((const char*)sc + (mi * 4 + ni) * 4096 + t8 * 16);
        acc[mi][ni] += o;
      }

#pragma unroll
    for (int mi = 0; mi < 4; mi++) {
#pragma unroll
      for (int ni = 0; ni < 4; ni++) {
        const int col = n0 + wc * 64 + ni * 16 + lc;
        const int rowb = m0 + wr * 64 + mi * 16 + lr * 4;
        if (MODE == 0) {
          const int qkv = col / 768;  // uniform per fragment (768 = 48*16)
          const int rem = col - qkv * 768;
          const int h = rem >> 6, d = rem & 63, fi = d >> 1;
          const float bb = (qkv == 0 ? bQ : qkv == 1 ? bK : bV)[rem];
#pragma unroll
          for (int r = 0; r < 4; r++) {
            const int grow = rowb + r;
            const int t = grow & 2047;
            float v = acc[mi][ni][r] + bb;
            float pv = __shfl_xor(v, 1);  // partner of the rope pair (adjacent col)
            if (qkv < 2) {
              const float c = cost[t * 32 + fi], s = sint[t * 32 + fi];
              float o = (d & 1) ? (pv * s + v * c) : (v * c - pv * s);
              if (qkv == 0) o *= 0.125f;  // fold 1/sqrt(64) into Q
              (qkv == 0 ? Qb : Kb)[(size_t)grow * 768 + rem] = f2bf(o);
            } else {
              const int bidx = grow >> 11;
              Vt[((size_t)(bidx * 12 + h) * 64 + d) * 2048 + t] = f2bf(v);
            }
          }
        } else {
          const float bb = bO[col];
#pragma unroll
          for (int r = 0; r < 4; r++) {
            const int grow = rowb + r;
            Out[(size_t)grow * 768 + col] = acc[mi][ni][r] + bb;
          }
        }
      }
    }
  }
#undef AS_
#undef BS_
}

// ---------------- causal flash attention (unchanged from R7) ----------------
__global__ __launch_bounds__(256, 2) void attn_kernel(
    const u16* __restrict__ Qb, const u16* __restrict__ Kb,
    const u16* __restrict__ Vt, u16* __restrict__ Ob) {
  __shared__ char Kls[4][8192];   // [buf][64 key rows][128B d]
  __shared__ char Vls[4][8192];   // [buf][64 d rows][128B keys]
  char* scratch = (char*)Kls;     // merge scratch (barrier-ordered reuse)

  const int id = blockIdx.x + 16 * blockIdx.y;
  const int s_ = id >> 3;
  const int bh = (id & 7) + 8 * (s_ % 3);  // same-bh blocks share an XCD
  const int xq = s_ / 3;                   // 0..15
  const int b = bh / 12, h = bh - b * 12;
  const int tid = threadIdx.x, w = tid >> 6, l = tid & 63;
  const int lq = l & 31, hi = l >> 5;
  const int qhalf = w & 1, grp = w >> 1;

  const u16* kbase = Kb + (size_t)(b * 2048) * 768 + h * 64;
  const u16* vbase = Vt + (size_t)(bh * 64) * 2048;

  const int r8 = l >> 3;
  const int scol8 = (l & 7) ^ r8;
  const u16* ksrc = kbase + (size_t)(w * 16 + r8) * 768 + scol8 * 8;
  const u16* vsrc = vbase + (size_t)(w * 16 + r8) * 2048 + scol8 * 8;

#define STAGE(t, bi)                                                        \
  {                                                                         \
    const size_t ko = (size_t)(t) * 64 * 768;                               \
    const int vo = (t) * 64;                                                \
    GLOAD16(ksrc + ko,            &Kls[bi][w * 2048]);                      \
    GLOAD16(ksrc + ko + 8 * 768,  &Kls[bi][w * 2048 + 1024]);               \
    GLOAD16(vsrc + vo,            &Vls[bi][w * 2048]);                      \
    GLOAD16(vsrc + vo + 8 * 2048, &Vls[bi][w * 2048 + 1024]);               \
  }

  const int fswz = (lq & 7) << 4;  // fragment-read XOR swizzle

#pragma unroll 1
  for (int half = 0; half < 2; half++) {
    const int qblk = half == 0 ? 31 - xq : xq;
    const int n = qblk + 1;          // kv tiles this phase
    const int nsup = (n + 1) >> 1;   // super-iterations

    bf16x8 qf[4];
    {
      const u16* qp = Qb + ((size_t)(b * 2048 + qblk * 64 + qhalf * 32 + lq)) * 768 +
                      h * 64 + hi * 8;
#pragma unroll
      for (int c = 0; c < 4; c++) qf[c] = *(const bf16x8*)(qp + c * 16);
    }

    float m_run = -INFINITY, l_run = 0.f;
    f32x16 acc2[2];
    acc2[0] = (f32x16)0.0f;
    acc2[1] = (f32x16)0.0f;

    STAGE(0, 0);
    if (n > 1) STAGE(1, 1);

    for (int p = 0; p < nsup; p++) {
      const int t0 = 2 * p;
      asm volatile("s_waitcnt vmcnt(0)" ::: "memory");  // tiles t0, t0+1 landed
      __builtin_amdgcn_s_barrier();
      __builtin_amdgcn_sched_barrier(0);
      if (t0 + 2 < n) STAGE(t0 + 2, (t0 + 2) & 3);
      if (t0 + 3 < n) STAGE(t0 + 3, (t0 + 3) & 3);

      const int tile = t0 + grp;
      if (tile < n) {
        const int cur = tile & 3;

        f32x16 s2[2];
        s2[0] = (f32x16)0.0f;
        s2[1] = (f32x16)0.0f;
        __builtin_amdgcn_s_setprio(1);
#pragma unroll
        for (int c = 0; c < 4; c++) {
          const int cb = (c * 32 + hi * 16) ^ fswz;
          bf16x8 kf0 = *(const bf16x8*)(&Kls[cur][lq * 128] + cb);
          bf16x8 kf1 = *(const bf16x8*)(&Kls[cur][(32 + lq) * 128] + cb);
          s2[0] = MFMA32(kf0, qf[c], s2[0]);
          s2[1] = MFMA32(kf1, qf[c], s2[1]);
        }
        __builtin_amdgcn_s_setprio(0);

        if (tile == qblk) {  // causal mask inside diagonal tile
          const int qrel = qhalf * 32 + lq;
#pragma unroll
          for (int kt2 = 0; kt2 < 2; kt2++)
#pragma unroll
            for (int r = 0; r < 16; r++) {
              const int ko = kt2 * 32 + (r & 3) + 8 * (r >> 2) + 4 * hi;
              if (ko > qrel) s2[kt2][r] = -INFINITY;
            }
        }

        float pm = s2[0][0];
#pragma unroll
        for (int r = 1; r < 16; r++) pm = fmaxf(pm, s2[0][r]);
#pragma unroll
        for (int r = 0; r < 16; r++) pm = fmaxf(pm, s2[1][r]);
        pm = fmaxf(pm, __shfl_xor(pm, 32));

        const float mn = fmaxf(m_run, pm);
        const float alpha = __expf(m_run - mn);
        m_run = mn;

        float rs = 0.f;
        u32 pk[2][8];
#pragma unroll
        for (int kt2 = 0; kt2 < 2; kt2++)
#pragma unroll
          for (int j = 0; j < 8; j++) {
            float p0 = __expf(s2[kt2][2 * j] - mn);
            float p1 = __expf(s2[kt2][2 * j + 1] - mn);
            rs += p0 + p1;
            asm("v_cvt_pk_bf16_f32 %0, %1, %2" : "=v"(pk[kt2][j]) : "v"(p0), "v"(p1));
          }
        l_run = l_run * alpha + rs;

        union { u32 u[4]; bf16x8 v; } pf[4];
#pragma unroll
        for (int kq = 0; kq < 4; kq++) {
          const int kt2 = kq >> 1, i0 = 4 * (kq & 1);
          u32 a0 = pk[kt2][i0], b0 = pk[kt2][i0 + 2];
          u32 a1 = pk[kt2][i0 + 1], b1 = pk[kt2][i0 + 3];
          asm("v_permlane32_swap_b32 %0, %1" : "+v"(a0), "+v"(b0));
          asm("v_permlane32_swap_b32 %0, %1" : "+v"(a1), "+v"(b1));
          pf[kq].u[0] = a0; pf[kq].u[1] = a1; pf[kq].u[2] = b0; pf[kq].u[3] = b1;
        }

#pragma unroll
        for (int dh = 0; dh < 2; dh++)
#pragma unroll
          for (int r = 0; r < 16; r++) acc2[dh][r] *= alpha;

        __builtin_amdgcn_s_setprio(1);
#pragma unroll
        for (int dh = 0; dh < 2; dh++) {
          const char* vr = &Vls[cur][(dh * 32 + lq) * 128];
#pragma unroll
          for (int kq = 0; kq < 4; kq++) {
            bf16x8 vf = *(const bf16x8*)(vr + ((kq * 32 + hi * 16) ^ fswz));
            acc2[dh] = MFMA32(vf, pf[kq].v, acc2[dh]);
          }
        }
        __builtin_amdgcn_s_setprio(0);
      }
    }

    // ---- merge the two kv-groups via LDS scratch ----
    asm volatile("s_waitcnt lgkmcnt(0)" ::: "memory");
    __builtin_amdgcn_s_barrier();  // A: all compute (and LDS reads) done
    if (grp == 1) {
      float* sc = (float*)scratch + ((size_t)(w - 2) * 64 + l) * 34;
#pragma unroll
      for (int dh = 0; dh < 2; dh++)
#pragma unroll
        for (int r = 0; r < 16; r++) sc[dh * 16 + r] = acc2[dh][r];
      sc[32] = m_run;
      sc[33] = l_run;
    }
    asm volatile("s_waitcnt lgkmcnt(0)" ::: "memory");
    __builtin_amdgcn_s_barrier();  // B: group-1 state visible
    if (grp == 0) {
      const float* sc = (const float*)scratch + ((size_t)w * 64 + l) * 34;
      const float m1 = sc[32], l1 = sc[33];
      const float M = fmaxf(m_run, m1);
      const float a0 = __expf(m_run - M);
      const float a1 = __expf(m1 - M);   // exp(-inf - finite) = 0 when group1 idle
      const float lm = l_run * a0 + l1 * a1;
      const float lt = lm + __shfl_xor(lm, 32);
      const float inv = 1.0f / lt;
      u16* ob = Ob + ((size_t)(b * 2048 + qblk * 64 + qhalf * 32 + lq)) * 768 + h * 64;
#pragma unroll
      for (int dh = 0; dh < 2; dh++)
#pragma unroll
        for (int g = 0; g < 4; g++) {
          ushort4 o4;
          o4.x = f2bf((acc2[dh][4 * g + 0] * a0 + sc[dh * 16 + 4 * g + 0] * a1) * inv);
          o4.y = f2bf((acc2[dh][4 * g + 1] * a0 + sc[dh * 16 + 4 * g + 1] * a1) * inv);
          o4.z = f2bf((acc2[dh][4 * g + 2] * a0 + sc[dh * 16 + 4 * g + 2] * a1) * inv);
          o4.w = f2bf((acc2[dh][4 * g + 3] * a0 + sc[dh * 16 + 4 * g + 3] * a1) * inv);
          *(ushort4*)(ob + dh * 32 + 8 * g + 4 * hi) = o4;
        }
    }
    asm volatile("s_waitcnt lgkmcnt(0)" ::: "memory");
    __builtin_amdgcn_s_barrier();  // C: scratch reads done before next-phase staging
  }
#undef STAGE
}

// ---------------- launcher ----------------

extern "C" void kernel_launch(void* const* d_in, const int* in_sizes, int n_in,
                              void* d_out, int out_size, void* d_ws, size_t ws_size,
                              hipStream_t stream) {
  const float* x  = (const float*)d_in[0];
  const float* WQ = (const float*)d_in[1];
  const float* bQ = (const float*)d_in[2];
  const float* WK = (const float*)d_in[3];
  const float* bK = (const float*)d_in[4];
  const float* WV = (const float*)d_in[5];
  const float* bV = (const float*)d_in[6];
  const float* WO = (const float*)d_in[7];
  const float* bO = (const float*)d_in[8];

  char* ws = (char*)d_ws;
  u16* Xb    = (u16*)(ws + 0);          // 4096x768 bf16
  u16* Wqkv  = (u16*)(ws + 6291456);    // 2304x768 bf16 (B^T)
  u16* WoT   = (u16*)(ws + 9830400);    // 768x768 bf16 (B^T)
  u16* Qb    = (u16*)(ws + 11010048);   // [B][T][768] bf16
  u16* Kb    = (u16*)(ws + 17301504);   // [B][T][768] bf16
  u16* Vt    = (u16*)(ws + 23592960);   // [bh][64][2048] bf16
  u16* Ob    = (u16*)(ws + 29884416);   // [B*T][768] bf16
  float* cost = (float*)(ws + 36175872); // [2048][32]
  float* sint = (float*)(ws + 36438016); // [2048][32]

  prep_all<<<5632, 256, 0, stream>>>(x, WQ, WK, WV, WO, cost, sint, Xb, Wqkv, WoT);

  gemm_bt<0><<<576, 512, 0, stream>>>(Xb, Wqkv, 768, 768, 768,
                                      bQ, bK, bV, cost, sint,
                                      Qb, Kb, Vt, nullptr, nullptr);
  attn_kernel<<<dim3(16, 24), 256, 0, stream>>>(Qb, Kb, Vt, Ob);
  gemm_bt<1><<<192, 512, 0, stream>>>(Ob, WoT, 768, 768, 768,
                                      nullptr, nullptr, nullptr, nullptr, nullptr,
                                      nullptr, nullptr, nullptr, bO, (float*)d_out);
}